// Round 6
// baseline (12964.378 us; speedup 1.0000x reference)
//
#include <hip/hip_runtime.h>
#include <hip/hip_cooperative_groups.h>
#include <cstddef>
#include <cstdint>

namespace cg = cooperative_groups;

// ---------------- problem constants ----------------
constexpr int CV    = 12000;
constexpr int CVP   = 12032;   // vocab padded to x64
constexpr int CWE   = 1000;
constexpr int CFEAT = 2048;
constexpr int CFE   = 1024;
constexpr int CH    = 1024;
constexpr int CAH   = 512;
constexpr int CNREG = 36;
constexpr int CB    = 128;
constexpr int CT    = 17;
constexpr int XBA   = 2048;    // xba = [h_lang | fc_e]
constexpr int XLG   = 2048;    // x_lang = [att_res | h_att]
constexpr int G4    = 4096;

#define CDIV(a,b) (((a)+(b)-1)/(b))

typedef __bf16 bf16_t;
typedef __bf16 bf16x8 __attribute__((ext_vector_type(8)));
typedef float  f32x4  __attribute__((ext_vector_type(4)));

struct Seg { const bf16_t* A; const bf16_t* W; int lda, ldw, kt; };

struct MegaArgs {
    const bf16_t *attl_wih, *attl_whh, *langl_wih, *langl_whh;
    const float  *attl_bih, *attl_bhh, *langl_bih, *langl_bhh;
    const bf16_t *w_all, *att_e, *h2att_wT;
    const float  *p_att, *h2att_b, *alpha_w, *alpha_b;
    bf16_t *xba, *x_lang, *h_all;
    float  *gpart, *c_att, *c_lang;
};

// =======================================================================
// Standalone GEMM (preamble + classifier). C = A @ W^T + b.
// 1D grid, XCD swizzle: MODE 1 = n-slow (share W per XCD; W >> A),
// MODE 2 = m-slow (share A per XCD; A >> W). Cols clipped at nclip.
// =======================================================================
template<bool RELU, bool OUTBF, int SWZMODE>
__global__ __launch_bounds__(256)
void gemm3(Seg s0, int inner, const float* __restrict__ bias1,
           void* __restrict__ Cout, int ldc, int nclip)
{
    const int tid = threadIdx.x;
    const int wid = tid >> 6, lane = tid & 63;
    const int wr = wid >> 1, wc = wid & 1;
    const int llo = lane & 15, lhi = lane >> 4;
    const int nb = gridDim.x, id = blockIdx.x;
    const int sw = (id & 7) * (nb >> 3) + (id >> 3);   // nb % 8 == 0
    int m0, n0;
    if (SWZMODE == 1) { n0 = (sw / inner) * 64; m0 = (sw % inner) * 128; }
    else              { m0 = (sw / inner) * 128; n0 = (sw % inner) * 64; }

    __shared__ __align__(16) uint8_t sm[2][24576];  // A [0,16384) | B [16384,24576)

    const int TT = s0.kt;
    f32x4 acc[4][2] = {};
    uint4 ra[4], rb[2];
    const int srow = tid >> 3, sc = tid & 7;
    const int cswz = (sc ^ (srow & 7)) << 4;

    auto load_tile = [&](int ti) {
        const int k0 = ti << 6;
        #pragma unroll
        for (int i = 0; i < 4; ++i)
            ra[i] = *(const uint4*)(s0.A + (size_t)(m0 + i * 32 + srow) * s0.lda + k0 + sc * 8);
        #pragma unroll
        for (int i = 0; i < 2; ++i)
            rb[i] = *(const uint4*)(s0.W + (size_t)(n0 + i * 32 + srow) * s0.ldw + k0 + sc * 8);
    };
    auto write_tile = [&](int buf) {
        uint8_t* base = sm[buf];
        #pragma unroll
        for (int i = 0; i < 4; ++i) *(uint4*)(base + (i * 32 + srow) * 128 + cswz) = ra[i];
        #pragma unroll
        for (int i = 0; i < 2; ++i) *(uint4*)(base + 16384 + (i * 32 + srow) * 128 + cswz) = rb[i];
    };
    auto compute = [&](int buf) {
        const uint8_t* base = sm[buf];
        const int r7 = llo & 7;
        #pragma unroll
        for (int kk = 0; kk < 2; ++kk) {
            const int coff = ((kk * 4 + lhi) ^ r7) << 4;   // permuted-k (same map A & B)
            bf16x8 af[4], bg[2];
            #pragma unroll
            for (int fm = 0; fm < 4; ++fm)
                af[fm] = *(const bf16x8*)(base + (wr * 64 + fm * 16 + llo) * 128 + coff);
            #pragma unroll
            for (int fn = 0; fn < 2; ++fn)
                bg[fn] = *(const bf16x8*)(base + 16384 + (wc * 32 + fn * 16 + llo) * 128 + coff);
            #pragma unroll
            for (int fm = 0; fm < 4; ++fm)
                #pragma unroll
                for (int fn = 0; fn < 2; ++fn)
                    acc[fm][fn] = __builtin_amdgcn_mfma_f32_16x16x32_bf16(
                        af[fm], bg[fn], acc[fm][fn], 0, 0, 0);
        }
    };

    load_tile(0); write_tile(0); __syncthreads();
    int cur = 0;
    for (int ti = 0; ti < TT; ++ti) {
        const bool more = (ti + 1 < TT);
        if (more) load_tile(ti + 1);
        compute(cur);
        __syncthreads();
        if (more) write_tile(cur ^ 1);
        __syncthreads();
        cur ^= 1;
    }

    const int colb = n0 + wc * 32;
    const int rowb = m0 + wr * 64 + lhi * 4;
    #pragma unroll
    for (int fn = 0; fn < 2; ++fn) {
        const int col = colb + fn * 16 + llo;
        if (col >= nclip) continue;
        const float b = bias1 ? bias1[col] : 0.f;
        #pragma unroll
        for (int fm = 0; fm < 4; ++fm)
            #pragma unroll
            for (int r = 0; r < 4; ++r) {
                float v = acc[fm][fn][r] + b;
                if (RELU) v = fmaxf(v, 0.f);
                const size_t off = (size_t)(rowb + fm * 16 + r) * ldc + col;
                if (OUTBF) ((bf16_t*)Cout)[off] = (bf16_t)v;
                else       ((float*) Cout)[off] = v;
            }
    }
}

// =======================================================================
// Recurrence phase device functions (shared by megakernel and fallback).
// =======================================================================
// per-block GEMM phase: M=128 (m0=0), one 64-col n-tile, k-tiles [ktb,kte).
template<int NSEG>
__device__ __forceinline__ void gemm_phase(
    uint8_t (*sm)[24576], const Seg* s, int n0, int ktb, int kte,
    const float* bias1, const float* bias2, bool withBias, float* outP)
{
    const int tid = threadIdx.x;
    const int wid = tid >> 6, lane = tid & 63;
    const int wr = wid >> 1, wc = wid & 1;
    const int llo = lane & 15, lhi = lane >> 4;
    f32x4 acc[4][2] = {};
    uint4 ra[4], rb[2];
    const int srow = tid >> 3, sc = tid & 7;
    const int cswz = (sc ^ (srow & 7)) << 4;

    auto load_tile = [&](int ti) {
        const bf16_t* As = s[0].A; const bf16_t* Ws = s[0].W;
        int la = s[0].lda, lw = s[0].ldw, rt = ti;
        if (NSEG > 1 && rt >= s[0].kt) {
            rt -= s[0].kt; As = s[1].A; Ws = s[1].W; la = s[1].lda; lw = s[1].ldw;
            if (NSEG > 2 && rt >= s[1].kt) {
                rt -= s[1].kt; As = s[2].A; Ws = s[2].W; la = s[2].lda; lw = s[2].ldw;
            }
        }
        const int k0 = rt << 6;
        #pragma unroll
        for (int i = 0; i < 4; ++i)
            ra[i] = *(const uint4*)(As + (size_t)(i * 32 + srow) * la + k0 + sc * 8);
        #pragma unroll
        for (int i = 0; i < 2; ++i)
            rb[i] = *(const uint4*)(Ws + (size_t)(n0 + i * 32 + srow) * lw + k0 + sc * 8);
    };
    auto write_tile = [&](int buf) {
        uint8_t* base = sm[buf];
        #pragma unroll
        for (int i = 0; i < 4; ++i) *(uint4*)(base + (i * 32 + srow) * 128 + cswz) = ra[i];
        #pragma unroll
        for (int i = 0; i < 2; ++i) *(uint4*)(base + 16384 + (i * 32 + srow) * 128 + cswz) = rb[i];
    };
    auto compute = [&](int buf) {
        const uint8_t* base = sm[buf];
        const int r7 = llo & 7;
        #pragma unroll
        for (int kk = 0; kk < 2; ++kk) {
            const int coff = ((kk * 4 + lhi) ^ r7) << 4;
            bf16x8 af[4], bg[2];
            #pragma unroll
            for (int fm = 0; fm < 4; ++fm)
                af[fm] = *(const bf16x8*)(base + (wr * 64 + fm * 16 + llo) * 128 + coff);
            #pragma unroll
            for (int fn = 0; fn < 2; ++fn)
                bg[fn] = *(const bf16x8*)(base + 16384 + (wc * 32 + fn * 16 + llo) * 128 + coff);
            #pragma unroll
            for (int fm = 0; fm < 4; ++fm)
                #pragma unroll
                for (int fn = 0; fn < 2; ++fn)
                    acc[fm][fn] = __builtin_amdgcn_mfma_f32_16x16x32_bf16(
                        af[fm], bg[fn], acc[fm][fn], 0, 0, 0);
        }
    };

    load_tile(ktb); write_tile(0); __syncthreads();
    int cur = 0;
    for (int ti = ktb; ti < kte; ++ti) {
        const bool more = (ti + 1 < kte);
        if (more) load_tile(ti + 1);
        compute(cur);
        __syncthreads();
        if (more) write_tile(cur ^ 1);
        __syncthreads();
        cur ^= 1;
    }

    const int colb = n0 + wc * 32;
    const int rowb = wr * 64 + lhi * 4;
    #pragma unroll
    for (int fn = 0; fn < 2; ++fn) {
        const int col = colb + fn * 16 + llo;
        const float bs = withBias ? (bias1[col] + bias2[col]) : 0.f;
        #pragma unroll
        for (int fm = 0; fm < 4; ++fm)
            #pragma unroll
            for (int r = 0; r < 4; ++r)
                outP[(size_t)(rowb + fm * 16 + r) * G4 + col] = acc[fm][fn][r] + bs;
    }
}

__device__ __forceinline__ void phaseA_dev(uint8_t (*sm)[24576], const MegaArgs& a,
                                           int t, int blk)
{
    const int n0 = (blk >> 3) * 64;
    const int z  = blk & 7;
    Seg s[3] = {{a.xba, a.attl_wih, XBA, 3072, 32},
                {a.w_all + (size_t)t * CB * 1024, a.attl_wih + 2048, 1024, 3072, 16},
                {a.x_lang + CH, a.attl_whh, XLG, CH, 16}};
    gemm_phase<3>(sm, s, n0, z * 8, z * 8 + 8,
                  a.attl_bih, a.attl_bhh, z == 0, a.gpart + (size_t)z * CB * G4);
}

__device__ __forceinline__ void phaseC_dev(uint8_t (*sm)[24576], const MegaArgs& a,
                                           int blk)
{
    const int n0 = (blk >> 3) * 64;
    const int z  = blk & 7;
    Seg s[2] = {{a.x_lang, a.langl_wih, XLG, 2048, 32},
                {a.xba, a.langl_whh, XBA, CH, 16}};
    gemm_phase<2>(sm, s, n0, z * 6, z * 6 + 6,
                  a.langl_bih, a.langl_bhh, z == 0, a.gpart + (size_t)z * CB * G4);
}

// fused: reduce 8 gate partials -> att-LSTM -> hq -> attention. smf >= 1664 floats.
__device__ void lstm_attn_dev(float* smf, int b, const MegaArgs& a)
{
    float* h      = smf;
    float* shq    = h + CH;
    float* se     = shq + CAH;
    float* salpha = se + 64;
    const int tid = threadIdx.x;

    #pragma unroll
    for (int k4 = 0; k4 < 4; ++k4) {
        const int j = tid + k4 * 256;
        float g0 = 0.f, g1 = 0.f, g2 = 0.f, g3 = 0.f;
        #pragma unroll
        for (int z = 0; z < 8; ++z) {
            const float* gp = a.gpart + (size_t)z * CB * G4 + (size_t)b * G4 + j;
            g0 += gp[0]; g1 += gp[1024]; g2 += gp[2048]; g3 += gp[3072];
        }
        const float si = 1.f / (1.f + expf(-g0));
        const float sf = 1.f / (1.f + expf(-g1));
        const float so = 1.f / (1.f + expf(-g3));
        const float cn = sf * a.c_att[b * CH + j] + si * tanhf(g2);
        const float hn = so * tanhf(cn);
        a.c_att[b * CH + j] = cn;
        h[j] = hn;
        a.x_lang[(size_t)b * XLG + CH + j] = (bf16_t)hn;
    }
    __syncthreads();

    for (int n = tid; n < CAH; n += 256) {
        const bf16_t* wrow = a.h2att_wT + (size_t)n * CH;
        float s = 0.f;
        for (int k = 0; k < CH; k += 8) {
            bf16x8 w8 = *(const bf16x8*)(wrow + k);
            #pragma unroll
            for (int q = 0; q < 8; ++q) s = fmaf((float)w8[q], h[k + q], s);
        }
        shq[n] = s + a.h2att_b[n];
    }
    __syncthreads();

    const int wave = tid >> 6, lane = tid & 63;
    for (int n = wave; n < CNREG; n += 4) {
        const float* pr = a.p_att + ((size_t)b * CNREG + n) * CAH;
        float s = 0.f;
        #pragma unroll
        for (int q = 0; q < CAH / 64; ++q) {
            const int d = lane + q * 64;
            s += a.alpha_w[d] * tanhf(pr[d] + shq[d]);
        }
        for (int off = 32; off; off >>= 1) s += __shfl_down(s, off);
        if (lane == 0) se[n] = s + a.alpha_b[0];
    }
    __syncthreads();

    float mx = -1e30f;
    for (int n = 0; n < CNREG; ++n) mx = fmaxf(mx, se[n]);
    float sum = 0.f;
    for (int n = 0; n < CNREG; ++n) sum += expf(se[n] - mx);
    if (tid < CNREG) salpha[tid] = expf(se[tid] - mx) / sum;
    __syncthreads();

    for (int d = tid; d < CFE; d += 256) {
        float s = 0.f;
        const bf16_t* ae = a.att_e + (size_t)b * CNREG * CFE + d;
        #pragma unroll 4
        for (int n = 0; n < CNREG; ++n) s = fmaf(salpha[n], (float)ae[(size_t)n * CFE], s);
        a.x_lang[(size_t)b * XLG + d] = (bf16_t)s;
    }
}

__device__ __forceinline__ void phaseD_dev(const MegaArgs& a, int t, int idx)
{
    const int b = idx >> 10, j = idx & (CH - 1);
    float g0 = 0.f, g1 = 0.f, g2 = 0.f, g3 = 0.f;
    #pragma unroll
    for (int zz = 0; zz < 8; ++zz) {
        const float* gp = a.gpart + (size_t)zz * CB * G4 + (size_t)b * G4 + j;
        g0 += gp[0]; g1 += gp[1024]; g2 += gp[2048]; g3 += gp[3072];
    }
    const float si = 1.f / (1.f + expf(-g0));
    const float sf = 1.f / (1.f + expf(-g1));
    const float so = 1.f / (1.f + expf(-g3));
    const float cn = sf * a.c_lang[idx] + si * tanhf(g2);
    const float hn = so * tanhf(cn);
    a.c_lang[idx] = cn;
    const bf16_t hb = (bf16_t)hn;
    a.xba[(size_t)b * XBA + j] = hb;
    a.h_all[((size_t)b * (CT - 1) + t) * CH + j] = hb;
}

// ---------------- persistent cooperative megakernel ----------------
__global__ __launch_bounds__(256, 2)
void mega(MegaArgs a)
{
    cg::grid_group grid = cg::this_grid();
    __shared__ __align__(16) uint8_t sm[2][24576];
    const int blk = blockIdx.x, tid = threadIdx.x;

    for (int t = 0; t < CT - 1; ++t) {
        phaseA_dev(sm, a, t, blk);
        __threadfence(); grid.sync(); __threadfence();

        if (blk < CB) lstm_attn_dev((float*)sm, blk, a);
        __threadfence(); grid.sync(); __threadfence();

        phaseC_dev(sm, a, blk);
        __threadfence(); grid.sync(); __threadfence();

        phaseD_dev(a, t, blk * 256 + tid);   // 512*256 == CB*CH
        __threadfence(); grid.sync(); __threadfence();
    }
}

// ---------------- fallback per-phase wrapper kernels ----------------
__global__ __launch_bounds__(256)
void phaseA_k(MegaArgs a, int t)
{
    __shared__ __align__(16) uint8_t sm[2][24576];
    phaseA_dev(sm, a, t, blockIdx.x);
}
__global__ __launch_bounds__(256)
void phaseB_k(MegaArgs a)
{
    __shared__ __align__(16) float smf[1664];
    lstm_attn_dev(smf, blockIdx.x, a);
}
__global__ __launch_bounds__(256)
void phaseC_k(MegaArgs a)
{
    __shared__ __align__(16) uint8_t sm[2][24576];
    phaseC_dev(sm, a, blockIdx.x);
}
__global__ __launch_bounds__(256)
void phaseD_k(MegaArgs a, int t)
{
    phaseD_dev(a, t, blockIdx.x * 256 + threadIdx.x);
}

// ---------------- small prep kernels ----------------
__global__ void convert_pad(const float* __restrict__ src, bf16_t* __restrict__ dst,
                            int C, int Cp)
{
    const int r = blockIdx.y;
    const int c = blockIdx.x * 256 + threadIdx.x;
    if (c >= Cp) return;
    dst[(size_t)r * Cp + c] = (c < C) ? (bf16_t)src[(size_t)r * C + c] : (bf16_t)0.f;
}

__global__ __launch_bounds__(256)
void transpose_convert(const float* __restrict__ src, bf16_t* __restrict__ dst,
                       int K, int N)
{
    __shared__ float tile[32][33];
    const int n0 = blockIdx.x * 32, k0 = blockIdx.y * 32;
    const int tx = threadIdx.x & 31, ty = threadIdx.x >> 5;   // 32 x 8
    #pragma unroll
    for (int i = 0; i < 4; ++i) {
        const int k = k0 + ty + i * 8, n = n0 + tx;
        tile[ty + i * 8][tx] = (k < K && n < N) ? src[(size_t)k * N + n] : 0.f;
    }
    __syncthreads();
    #pragma unroll
    for (int i = 0; i < 4; ++i) {
        const int n = n0 + ty + i * 8, k = k0 + tx;
        if (n < N && k < K) dst[(size_t)n * K + k] = (bf16_t)tile[tx][ty + i * 8];
    }
}

__global__ void emb_all(const float* __restrict__ emb_w,
                        const int* __restrict__ captions, bf16_t* __restrict__ w_all)
{
    const int r = blockIdx.y;                       // t*128 + b
    const int j = blockIdx.x * 256 + threadIdx.x;   // 0..1023
    const int t = r >> 7, b = r & 127;
    const int tok = captions[b * CT + t];
    const float v = (j < CWE) ? fmaxf(emb_w[(size_t)tok * CWE + j], 0.f) : 0.f;
    w_all[(size_t)r * 1024 + j] = (bf16_t)v;
}

// ---- in-place log-softmax over each of 2048 rows of out (length 12000) ----
__global__ __launch_bounds__(256)
void logsoftmax_inplace(float* __restrict__ out)
{
    __shared__ float red[4];
    const int r = blockIdx.x, tid = threadIdx.x;
    float* row = out + (size_t)r * CV;
    constexpr int NI = 47;   // 47*256 >= 12000

    float v[NI];
    float mx = -1e30f;
    #pragma unroll
    for (int i = 0; i < NI; ++i) {
        const int j = tid + i * 256;
        v[i] = (j < CV) ? row[j] : -1e30f;
        mx = fmaxf(mx, v[i]);
    }
    for (int off = 32; off; off >>= 1) mx = fmaxf(mx, __shfl_down(mx, off));
    if ((tid & 63) == 0) red[tid >> 6] = mx;
    __syncthreads();
    mx = fmaxf(fmaxf(red[0], red[1]), fmaxf(red[2], red[3]));
    __syncthreads();

    float sum = 0.f;
    #pragma unroll
    for (int i = 0; i < NI; ++i)
        if (tid + i * 256 < CV) sum += expf(v[i] - mx);
    for (int off = 32; off; off >>= 1) sum += __shfl_down(sum, off);
    if ((tid & 63) == 0) red[tid >> 6] = sum;
    __syncthreads();
    sum = red[0] + red[1] + red[2] + red[3];
    const float lse = mx + logf(sum);

    #pragma unroll
    for (int i = 0; i < NI; ++i) {
        const int j = tid + i * 256;
        if (j < CV) row[j] = v[i] - lse;
    }
}

// ---------------- launch ----------------
extern "C" void kernel_launch(void* const* d_in, const int* in_sizes, int n_in,
                              void* d_out, int out_size, void* d_ws, size_t ws_size,
                              hipStream_t stream)
{
    const float* fc_feats  = (const float*)d_in[0];
    const float* att_feats = (const float*)d_in[1];
    const int*   captions  = (const int*)  d_in[2];
    const float* emb_w     = (const float*)d_in[3];
    const float* fc_w      = (const float*)d_in[4];
    const float* fc_b      = (const float*)d_in[5];
    const float* atte_w    = (const float*)d_in[6];
    const float* atte_b    = (const float*)d_in[7];
    const float* ctx_w     = (const float*)d_in[8];
    const float* ctx_b     = (const float*)d_in[9];
    const float* attl_wih  = (const float*)d_in[10];
    const float* attl_whh  = (const float*)d_in[11];
    const float* attl_bih  = (const float*)d_in[12];
    const float* attl_bhh  = (const float*)d_in[13];
    const float* h2att_w   = (const float*)d_in[14];
    const float* h2att_b   = (const float*)d_in[15];
    const float* alpha_w   = (const float*)d_in[16];
    const float* alpha_b   = (const float*)d_in[17];
    const float* langl_wih = (const float*)d_in[18];
    const float* langl_whh = (const float*)d_in[19];
    const float* langl_bih = (const float*)d_in[20];
    const float* langl_bhh = (const float*)d_in[21];
    const float* cls_w     = (const float*)d_in[22];
    const float* cls_b     = (const float*)d_in[23];

    float* out = (float*)d_out;

    // ---- workspace layout ----
    char* p = (char*)d_ws;
    auto alloc_bf = [&](size_t e) { bf16_t* q = (bf16_t*)p; p += e * 2; return q; };
    auto alloc_f  = [&](size_t e) { float*  q = (float*) p; p += e * 4; return q; };

    bf16_t* attl_wih_b  = alloc_bf((size_t)G4 * 3072);
    bf16_t* attl_whh_b  = alloc_bf((size_t)G4 * CH);
    bf16_t* langl_wih_b = alloc_bf((size_t)G4 * 2048);
    bf16_t* langl_whh_b = alloc_bf((size_t)G4 * CH);
    bf16_t* fc_wT_b     = alloc_bf((size_t)CFE * CFEAT);
    bf16_t* atte_wT_b   = alloc_bf((size_t)CFE * CFEAT);
    bf16_t* ctx_wT_b    = alloc_bf((size_t)CAH * CFE);
    bf16_t* h2att_wT_b  = alloc_bf((size_t)CAH * CH);
    bf16_t* cls_wT_b    = alloc_bf((size_t)CVP * CH);
    bf16_t* fc_feats_b  = alloc_bf((size_t)CB * CFEAT);
    bf16_t* att_feats_b = alloc_bf((size_t)CB * CNREG * CFEAT);
    bf16_t* att_e_b     = alloc_bf((size_t)CB * CNREG * CFE);
    bf16_t* w_all       = alloc_bf((size_t)(CT - 1) * CB * 1024);
    bf16_t* xba         = alloc_bf((size_t)CB * XBA);
    bf16_t* x_lang      = alloc_bf((size_t)CB * XLG);
    bf16_t* h_all       = alloc_bf((size_t)CB * (CT - 1) * CH);
    float*  p_att       = alloc_f ((size_t)CB * CNREG * CAH);
    float*  gpart       = alloc_f ((size_t)8 * CB * G4);
    float*  c_att       = alloc_f ((size_t)CB * CH);
    float*  c_lang      = alloc_f ((size_t)CB * CH);

    // ---- zero state ----
    hipMemsetAsync(xba,    0, (size_t)CB * XBA * 2, stream);
    hipMemsetAsync(x_lang, 0, (size_t)CB * XLG * 2, stream);
    hipMemsetAsync(c_att,  0, (size_t)CB * CH * 4, stream);
    hipMemsetAsync(c_lang, 0, (size_t)CB * CH * 4, stream);
    hipMemsetAsync(cls_wT_b + (size_t)CV * CH, 0, (size_t)(CVP - CV) * CH * 2, stream);

    const dim3 blk(256);
    auto mk = [](const bf16_t* A, int lda, const bf16_t* W, int ldw, int K) {
        return Seg{A, W, lda, ldw, K >> 6};
    };

    // ---- one-time conversions ----
    convert_pad<<<dim3(12, G4), blk, 0, stream>>>(attl_wih, attl_wih_b, 3048, 3072);
    convert_pad<<<dim3(4,  G4), blk, 0, stream>>>(attl_whh, attl_whh_b, CH, CH);
    convert_pad<<<dim3(8,  G4), blk, 0, stream>>>(langl_wih, langl_wih_b, 2048, 2048);
    convert_pad<<<dim3(4,  G4), blk, 0, stream>>>(langl_whh, langl_whh_b, CH, CH);
    convert_pad<<<dim3(8,  CB), blk, 0, stream>>>(fc_feats, fc_feats_b, CFEAT, CFEAT);
    convert_pad<<<dim3(8,  CB * CNREG), blk, 0, stream>>>(att_feats, att_feats_b, CFEAT, CFEAT);
    transpose_convert<<<dim3(CFE/32, CFEAT/32), blk, 0, stream>>>(fc_w,    fc_wT_b,    CFEAT, CFE);
    transpose_convert<<<dim3(CFE/32, CFEAT/32), blk, 0, stream>>>(atte_w,  atte_wT_b,  CFEAT, CFE);
    transpose_convert<<<dim3(CAH/32, CFE/32),   blk, 0, stream>>>(ctx_w,   ctx_wT_b,   CFE,   CAH);
    transpose_convert<<<dim3(CAH/32, CH/32),    blk, 0, stream>>>(h2att_w, h2att_wT_b, CH,    CAH);
    transpose_convert<<<dim3(CDIV(CV,32), CH/32), blk, 0, stream>>>(cls_w, cls_wT_b,   CH,    CV);
    emb_all<<<dim3(4, (CT - 1) * CB), blk, 0, stream>>>(emb_w, captions, w_all);

    // ---- preamble GEMMs (MODE2: A-panel clustered per XCD; A >> W here) ----
    gemm3<true,true,2><<<16, blk, 0, stream>>>(
        mk(fc_feats_b, CFEAT, fc_wT_b, CFEAT, CFEAT), 16, fc_b, xba + CH, XBA, 1 << 30);
    gemm3<true,true,2><<<576, blk, 0, stream>>>(
        mk(att_feats_b, CFEAT, atte_wT_b, CFEAT, CFEAT), 16, atte_b, att_e_b, CFE, 1 << 30);
    gemm3<false,false,2><<<288, blk, 0, stream>>>(
        mk(att_e_b, CFE, ctx_wT_b, CFE, CFE), 8, ctx_b, p_att, CAH, 1 << 30);

    // ---- recurrence: cooperative megakernel, fallback to per-phase launches ----
    MegaArgs ma;
    ma.attl_wih = attl_wih_b;  ma.attl_whh = attl_whh_b;
    ma.langl_wih = langl_wih_b; ma.langl_whh = langl_whh_b;
    ma.attl_bih = attl_bih;    ma.attl_bhh = attl_bhh;
    ma.langl_bih = langl_bih;  ma.langl_bhh = langl_bhh;
    ma.w_all = w_all;          ma.att_e = att_e_b;
    ma.h2att_wT = h2att_wT_b;  ma.p_att = p_att;
    ma.h2att_b = h2att_b;      ma.alpha_w = alpha_w;  ma.alpha_b = alpha_b;
    ma.xba = xba;              ma.x_lang = x_lang;    ma.h_all = h_all;
    ma.gpart = gpart;          ma.c_att = c_att;      ma.c_lang = c_lang;

    void* kargs[] = { (void*)&ma };
    hipError_t ce = hipLaunchCooperativeKernel((const void*)mega, dim3(512), dim3(256),
                                               kargs, 0, stream);
    if (ce != hipSuccess) {
        (void)hipGetLastError();   // clear sticky error; run fallback path
        for (int t = 0; t < CT - 1; ++t) {
            phaseA_k<<<512, blk, 0, stream>>>(ma, t);
            phaseB_k<<<CB,  blk, 0, stream>>>(ma);
            phaseC_k<<<512, blk, 0, stream>>>(ma);
            phaseD_k<<<512, blk, 0, stream>>>(ma, t);
        }
    }

    // ---- deferred classifier over all timesteps: [2048,1024] @ W^T -> out ----
    gemm3<false,false,1><<<(CVP/64) * (2048/128), blk, 0, stream>>>(
        mk(h_all, CH, cls_wT_b, CH, CH), 16, cls_b, out, CV, CV);

    logsoftmax_inplace<<<2048, blk, 0, stream>>>(out);
}

// Round 7
// 4054.134 us; speedup vs baseline: 3.1978x; 3.1978x over previous
//
#include <hip/hip_runtime.h>
#include <cstddef>
#include <cstdint>

// ---------------- problem constants ----------------
constexpr int CV    = 12000;
constexpr int CVP   = 12032;   // vocab padded to x64
constexpr int CWE   = 1000;
constexpr int CFEAT = 2048;
constexpr int CFE   = 1024;
constexpr int CH    = 1024;
constexpr int CAH   = 512;
constexpr int CNREG = 36;
constexpr int CB    = 128;
constexpr int CT    = 17;
constexpr int XBA   = 2048;    // xba = [h_lang | fc_e]
constexpr int XLG   = 2048;    // x_lang = [att_res | h_att]
constexpr int G4    = 4096;

#define CDIV(a,b) (((a)+(b)-1)/(b))

typedef __bf16 bf16_t;
typedef __bf16 bf16x8 __attribute__((ext_vector_type(8)));
typedef float  f32x4  __attribute__((ext_vector_type(4)));

struct Seg { const bf16_t* A; const bf16_t* W; int lda, ldw, kt; };

// =======================================================================
// Standalone GEMM (preamble + classifier). C = A @ W^T + b. BK=64.
// 1D grid, XCD swizzle: MODE 1 = n-slow (share W per XCD; W >> A),
// MODE 2 = m-slow (share A per XCD; A >> W). Cols clipped at nclip.
// =======================================================================
template<bool RELU, bool OUTBF, int SWZMODE>
__global__ __launch_bounds__(256)
void gemm3(Seg s0, int inner, const float* __restrict__ bias1,
           void* __restrict__ Cout, int ldc, int nclip)
{
    const int tid = threadIdx.x;
    const int wid = tid >> 6, lane = tid & 63;
    const int wr = wid >> 1, wc = wid & 1;
    const int llo = lane & 15, lhi = lane >> 4;
    const int nb = gridDim.x, id = blockIdx.x;
    const int sw = (id & 7) * (nb >> 3) + (id >> 3);   // nb % 8 == 0
    int m0, n0;
    if (SWZMODE == 1) { n0 = (sw / inner) * 64; m0 = (sw % inner) * 128; }
    else              { m0 = (sw / inner) * 128; n0 = (sw % inner) * 64; }

    __shared__ __align__(16) uint8_t sm[2][24576];  // A [0,16384) | B [16384,24576)

    const int TT = s0.kt;
    f32x4 acc[4][2] = {};
    uint4 ra[4], rb[2];
    const int srow = tid >> 3, sc = tid & 7;
    const int cswz = (sc ^ (srow & 7)) << 4;

    auto load_tile = [&](int ti) {
        const int k0 = ti << 6;
        #pragma unroll
        for (int i = 0; i < 4; ++i)
            ra[i] = *(const uint4*)(s0.A + (size_t)(m0 + i * 32 + srow) * s0.lda + k0 + sc * 8);
        #pragma unroll
        for (int i = 0; i < 2; ++i)
            rb[i] = *(const uint4*)(s0.W + (size_t)(n0 + i * 32 + srow) * s0.ldw + k0 + sc * 8);
    };
    auto write_tile = [&](int buf) {
        uint8_t* base = sm[buf];
        #pragma unroll
        for (int i = 0; i < 4; ++i) *(uint4*)(base + (i * 32 + srow) * 128 + cswz) = ra[i];
        #pragma unroll
        for (int i = 0; i < 2; ++i) *(uint4*)(base + 16384 + (i * 32 + srow) * 128 + cswz) = rb[i];
    };
    auto compute = [&](int buf) {
        const uint8_t* base = sm[buf];
        const int r7 = llo & 7;
        #pragma unroll
        for (int kk = 0; kk < 2; ++kk) {
            const int coff = ((kk * 4 + lhi) ^ r7) << 4;   // permuted-k (same map A & B)
            bf16x8 af[4], bg[2];
            #pragma unroll
            for (int fm = 0; fm < 4; ++fm)
                af[fm] = *(const bf16x8*)(base + (wr * 64 + fm * 16 + llo) * 128 + coff);
            #pragma unroll
            for (int fn = 0; fn < 2; ++fn)
                bg[fn] = *(const bf16x8*)(base + 16384 + (wc * 32 + fn * 16 + llo) * 128 + coff);
            #pragma unroll
            for (int fm = 0; fm < 4; ++fm)
                #pragma unroll
                for (int fn = 0; fn < 2; ++fn)
                    acc[fm][fn] = __builtin_amdgcn_mfma_f32_16x16x32_bf16(
                        af[fm], bg[fn], acc[fm][fn], 0, 0, 0);
        }
    };

    load_tile(0); write_tile(0); __syncthreads();
    int cur = 0;
    for (int ti = 0; ti < TT; ++ti) {
        const bool more = (ti + 1 < TT);
        if (more) load_tile(ti + 1);
        compute(cur);
        __syncthreads();
        if (more) write_tile(cur ^ 1);
        __syncthreads();
        cur ^= 1;
    }

    const int colb = n0 + wc * 32;
    const int rowb = m0 + wr * 64 + lhi * 4;
    #pragma unroll
    for (int fn = 0; fn < 2; ++fn) {
        const int col = colb + fn * 16 + llo;
        if (col >= nclip) continue;
        const float b = bias1 ? bias1[col] : 0.f;
        #pragma unroll
        for (int fm = 0; fm < 4; ++fm)
            #pragma unroll
            for (int r = 0; r < 4; ++r) {
                float v = acc[fm][fn][r] + b;
                if (RELU) v = fmaxf(v, 0.f);
                const size_t off = (size_t)(rowb + fm * 16 + r) * ldc + col;
                if (OUTBF) ((bf16_t*)Cout)[off] = (bf16_t)v;
                else       ((float*) Cout)[off] = v;
            }
    }
}

// =======================================================================
// gate_lstm: full-K gate GEMM with fused LSTM epilogue.
// Weights pre-permuted: row r' = 4*j + gate  (gate in {i,f,g,o}).
// Tile 64x16, grid (256 n-tiles, 2 m-tiles), BK=128, double-buffered LDS.
// Epilogue: 4-lane shfl gathers i,f,g,o; lanes split the stores:
//   gate0 -> hdst1 (bf16), gate1 -> hdst2 (bf16, opt), gate2 -> cstate,
//   gate3 -> hdst3 (fp32, opt).
// =======================================================================
template<int NSEG>
__global__ __launch_bounds__(256)
void gate_lstm(Seg s0, Seg s1, Seg s2, const float* __restrict__ cbias,
               float* __restrict__ cstate,
               bf16_t* __restrict__ hdst1, int ld1,
               bf16_t* __restrict__ hdst2, int ld2,
               float* __restrict__ hdst3)
{
    const int tid = threadIdx.x;
    const int w = tid >> 6, lane = tid & 63;
    const int llo = lane & 15, lhi = lane >> 4;
    const int nt = blockIdx.x;          // 0..255 (16 permuted cols each)
    const int m0 = blockIdx.y * 64;
    const int n0 = nt * 16;

    __shared__ __align__(16) uint8_t smA[2][16384];   // 64 rows x 256B
    __shared__ __align__(16) uint8_t smB[2][4096];    // 16 rows x 256B

    const int TT = s0.kt + (NSEG > 1 ? s1.kt : 0) + (NSEG > 2 ? s2.kt : 0);
    f32x4 acc = {0.f, 0.f, 0.f, 0.f};
    uint4 ra[4], rb;

    auto load_tile = [&](int ti) {
        const bf16_t* As = s0.A; const bf16_t* Ws = s0.W;
        int la = s0.lda, lw = s0.ldw, rt = ti;
        if (NSEG > 1 && rt >= s0.kt) {
            rt -= s0.kt; As = s1.A; Ws = s1.W; la = s1.lda; lw = s1.ldw;
            if (NSEG > 2 && rt >= s1.kt) {
                rt -= s1.kt; As = s2.A; Ws = s2.W; la = s2.lda; lw = s2.ldw;
            }
        }
        const int k0 = rt << 7;    // BK = 128
        #pragma unroll
        for (int i = 0; i < 4; ++i) {
            const int q = tid + i * 256;       // 0..1023
            const int row = q >> 4, c = q & 15;
            ra[i] = *(const uint4*)(As + (size_t)(m0 + row) * la + k0 + c * 8);
        }
        {
            const int row = tid >> 4, c = tid & 15;   // 256 chunks exactly
            rb = *(const uint4*)(Ws + (size_t)(n0 + row) * lw + k0 + c * 8);
        }
    };
    auto write_tile = [&](int buf) {
        #pragma unroll
        for (int i = 0; i < 4; ++i) {
            const int q = tid + i * 256;
            const int row = q >> 4, c = q & 15;
            *(uint4*)(smA[buf] + row * 256 + ((c ^ (row & 7)) << 4)) = ra[i];
        }
        {
            const int row = tid >> 4, c = tid & 15;
            *(uint4*)(smB[buf] + row * 256 + ((c ^ (row & 7)) << 4)) = rb;
        }
    };
    auto compute = [&](int buf) {
        const int r7 = llo & 7;
        #pragma unroll
        for (int kk = 0; kk < 4; ++kk) {
            const int coff = ((kk * 4 + lhi) ^ r7) << 4;   // 4-bit chunk, XOR low 3 bits
            bf16x8 a  = *(const bf16x8*)(smA[buf] + (w * 16 + llo) * 256 + coff);
            bf16x8 bb = *(const bf16x8*)(smB[buf] + llo * 256 + coff);
            acc = __builtin_amdgcn_mfma_f32_16x16x32_bf16(a, bb, acc, 0, 0, 0);
        }
    };

    load_tile(0); write_tile(0); __syncthreads();
    int cur = 0;
    for (int ti = 0; ti < TT; ++ti) {
        const bool more = (ti + 1 < TT);
        if (more) load_tile(ti + 1);
        compute(cur);
        __syncthreads();
        if (more) write_tile(cur ^ 1);
        __syncthreads();
        cur ^= 1;
    }

    // ---- LSTM epilogue ----
    const int gate = llo & 3;
    const int jg   = nt * 4 + (llo >> 2);    // global output unit
    const float bsum = cbias[n0 + llo];
    const int base = lane & ~3;
    const int rowb = m0 + w * 16 + lhi * 4;
    #pragma unroll
    for (int r = 0; r < 4; ++r) {
        const float v  = acc[r] + bsum;
        const float gi = __shfl(v, base + 0);
        const float gf = __shfl(v, base + 1);
        const float gg = __shfl(v, base + 2);
        const float go = __shfl(v, base + 3);
        const int b = rowb + r;
        const float cold = cstate[b * CH + jg];
        const float si = 1.f / (1.f + expf(-gi));
        const float sf = 1.f / (1.f + expf(-gf));
        const float so = 1.f / (1.f + expf(-go));
        const float cn = sf * cold + si * tanhf(gg);
        const float hn = so * tanhf(cn);
        if (gate == 0)      hdst1[(size_t)b * ld1 + jg] = (bf16_t)hn;
        else if (gate == 1) { if (hdst2) hdst2[(size_t)b * ld2 + jg] = (bf16_t)hn; }
        else if (gate == 2) cstate[b * CH + jg] = cn;
        else                { if (hdst3) hdst3[b * CH + jg] = hn; }
    }
}

// ---------------- attention: hq + e + softmax + weighted sum ----------------
__global__ __launch_bounds__(256)
void attn_k(const float* __restrict__ p_att, const float* __restrict__ h_att_f,
            const bf16_t* __restrict__ h2att_wT, const float* __restrict__ h2att_b,
            const bf16_t* __restrict__ att_e, const float* __restrict__ alpha_w,
            const float* __restrict__ alpha_b, bf16_t* __restrict__ x_lang)
{
    __shared__ float sh[CH];
    __shared__ float shq[CAH];
    __shared__ float se[CNREG], salpha[CNREG];
    const int b = blockIdx.x, tid = threadIdx.x;

    for (int j = tid; j < CH; j += 256) sh[j] = h_att_f[b * CH + j];
    __syncthreads();

    for (int n = tid; n < CAH; n += 256) {
        const bf16_t* wrow = h2att_wT + (size_t)n * CH;
        float s = 0.f;
        for (int k = 0; k < CH; k += 8) {
            bf16x8 w8 = *(const bf16x8*)(wrow + k);
            #pragma unroll
            for (int q = 0; q < 8; ++q) s = fmaf((float)w8[q], sh[k + q], s);
        }
        shq[n] = s + h2att_b[n];
    }
    __syncthreads();

    const int wave = tid >> 6, lane = tid & 63;
    for (int n = wave; n < CNREG; n += 4) {
        const float* pr = p_att + ((size_t)b * CNREG + n) * CAH;
        float s = 0.f;
        #pragma unroll
        for (int q = 0; q < CAH / 64; ++q) {
            const int d = lane + q * 64;
            s += alpha_w[d] * tanhf(pr[d] + shq[d]);
        }
        for (int off = 32; off; off >>= 1) s += __shfl_down(s, off);
        if (lane == 0) se[n] = s + alpha_b[0];
    }
    __syncthreads();

    float mx = -1e30f;
    for (int n = 0; n < CNREG; ++n) mx = fmaxf(mx, se[n]);
    float sum = 0.f;
    for (int n = 0; n < CNREG; ++n) sum += expf(se[n] - mx);
    if (tid < CNREG) salpha[tid] = expf(se[tid] - mx) / sum;
    __syncthreads();

    for (int d = tid; d < CFE; d += 256) {
        float s = 0.f;
        const bf16_t* ae = att_e + (size_t)b * CNREG * CFE + d;
        #pragma unroll 4
        for (int n = 0; n < CNREG; ++n) s = fmaf(salpha[n], (float)ae[(size_t)n * CFE], s);
        x_lang[(size_t)b * XLG + d] = (bf16_t)s;
    }
}

// ---------------- prep kernels ----------------
__global__ void convert_pad(const float* __restrict__ src, bf16_t* __restrict__ dst,
                            int C, int Cp)
{
    const int r = blockIdx.y;
    const int c = blockIdx.x * 256 + threadIdx.x;
    if (c >= Cp) return;
    dst[(size_t)r * Cp + c] = (c < C) ? (bf16_t)src[(size_t)r * C + c] : (bf16_t)0.f;
}

// gate-interleave row permutation: dst row r' = src row (r'&3)*1024 + (r'>>2)
__global__ void convert_perm(const float* __restrict__ src, bf16_t* __restrict__ dst,
                             int C, int Cp)
{
    const int rp = blockIdx.y;
    const int c = blockIdx.x * 256 + threadIdx.x;
    if (c >= Cp) return;
    const int rs = (rp & 3) * 1024 + (rp >> 2);
    dst[(size_t)rp * Cp + c] = (c < C) ? (bf16_t)src[(size_t)rs * C + c] : (bf16_t)0.f;
}

__global__ void bias_perm(const float* __restrict__ bih, const float* __restrict__ bhh,
                          float* __restrict__ dst)
{
    const int rp = blockIdx.x * 256 + threadIdx.x;
    if (rp >= G4) return;
    const int rs = (rp & 3) * 1024 + (rp >> 2);
    dst[rp] = bih[rs] + bhh[rs];
}

__global__ __launch_bounds__(256)
void transpose_convert(const float* __restrict__ src, bf16_t* __restrict__ dst,
                       int K, int N)
{
    __shared__ float tile[32][33];
    const int n0 = blockIdx.x * 32, k0 = blockIdx.y * 32;
    const int tx = threadIdx.x & 31, ty = threadIdx.x >> 5;   // 32 x 8
    #pragma unroll
    for (int i = 0; i < 4; ++i) {
        const int k = k0 + ty + i * 8, n = n0 + tx;
        tile[ty + i * 8][tx] = (k < K && n < N) ? src[(size_t)k * N + n] : 0.f;
    }
    __syncthreads();
    #pragma unroll
    for (int i = 0; i < 4; ++i) {
        const int n = n0 + ty + i * 8, k = k0 + tx;
        if (n < N && k < K) dst[(size_t)n * K + k] = (bf16_t)tile[tx][ty + i * 8];
    }
}

__global__ void emb_all(const float* __restrict__ emb_w,
                        const int* __restrict__ captions, bf16_t* __restrict__ w_all)
{
    const int r = blockIdx.y;                       // t*128 + b
    const int j = blockIdx.x * 256 + threadIdx.x;   // 0..1023
    const int t = r >> 7, b = r & 127;
    const int tok = captions[b * CT + t];
    const float v = (j < CWE) ? fmaxf(emb_w[(size_t)tok * CWE + j], 0.f) : 0.f;
    w_all[(size_t)r * 1024 + j] = (bf16_t)v;
}

// ---- in-place log-softmax over each of 2048 rows of out (length 12000) ----
__global__ __launch_bounds__(256)
void logsoftmax_inplace(float* __restrict__ out)
{
    __shared__ float red[4];
    const int r = blockIdx.x, tid = threadIdx.x;
    float* row = out + (size_t)r * CV;
    constexpr int NI = 47;   // 47*256 >= 12000

    float v[NI];
    float mx = -1e30f;
    #pragma unroll
    for (int i = 0; i < NI; ++i) {
        const int j = tid + i * 256;
        v[i] = (j < CV) ? row[j] : -1e30f;
        mx = fmaxf(mx, v[i]);
    }
    for (int off = 32; off; off >>= 1) mx = fmaxf(mx, __shfl_down(mx, off));
    if ((tid & 63) == 0) red[tid >> 6] = mx;
    __syncthreads();
    mx = fmaxf(fmaxf(red[0], red[1]), fmaxf(red[2], red[3]));
    __syncthreads();

    float sum = 0.f;
    #pragma unroll
    for (int i = 0; i < NI; ++i)
        if (tid + i * 256 < CV) sum += expf(v[i] - mx);
    for (int off = 32; off; off >>= 1) sum += __shfl_down(sum, off);
    if ((tid & 63) == 0) red[tid >> 6] = sum;
    __syncthreads();
    sum = red[0] + red[1] + red[2] + red[3];
    const float lse = mx + logf(sum);

    #pragma unroll
    for (int i = 0; i < NI; ++i) {
        const int j = tid + i * 256;
        if (j < CV) row[j] = v[i] - lse;
    }
}

// ---------------- launch ----------------
extern "C" void kernel_launch(void* const* d_in, const int* in_sizes, int n_in,
                              void* d_out, int out_size, void* d_ws, size_t ws_size,
                              hipStream_t stream)
{
    const float* fc_feats  = (const float*)d_in[0];
    const float* att_feats = (const float*)d_in[1];
    const int*   captions  = (const int*)  d_in[2];
    const float* emb_w     = (const float*)d_in[3];
    const float* fc_w      = (const float*)d_in[4];
    const float* fc_b      = (const float*)d_in[5];
    const float* atte_w    = (const float*)d_in[6];
    const float* atte_b    = (const float*)d_in[7];
    const float* ctx_w     = (const float*)d_in[8];
    const float* ctx_b     = (const float*)d_in[9];
    const float* attl_wih  = (const float*)d_in[10];
    const float* attl_whh  = (const float*)d_in[11];
    const float* attl_bih  = (const float*)d_in[12];
    const float* attl_bhh  = (const float*)d_in[13];
    const float* h2att_w   = (const float*)d_in[14];
    const float* h2att_b   = (const float*)d_in[15];
    const float* alpha_w   = (const float*)d_in[16];
    const float* alpha_b   = (const float*)d_in[17];
    const float* langl_wih = (const float*)d_in[18];
    const float* langl_whh = (const float*)d_in[19];
    const float* langl_bih = (const float*)d_in[20];
    const float* langl_bhh = (const float*)d_in[21];
    const float* cls_w     = (const float*)d_in[22];
    const float* cls_b     = (const float*)d_in[23];

    float* out = (float*)d_out;

    // ---- workspace layout ----
    char* p = (char*)d_ws;
    auto alloc_bf = [&](size_t e) { bf16_t* q = (bf16_t*)p; p += e * 2; return q; };
    auto alloc_f  = [&](size_t e) { float*  q = (float*) p; p += e * 4; return q; };

    bf16_t* attl_wih_p  = alloc_bf((size_t)G4 * 3072);   // permuted rows, padded cols
    bf16_t* attl_whh_p  = alloc_bf((size_t)G4 * CH);
    bf16_t* langl_wih_p = alloc_bf((size_t)G4 * 2048);
    bf16_t* langl_whh_p = alloc_bf((size_t)G4 * CH);
    bf16_t* fc_wT_b     = alloc_bf((size_t)CFE * CFEAT);
    bf16_t* atte_wT_b   = alloc_bf((size_t)CFE * CFEAT);
    bf16_t* ctx_wT_b    = alloc_bf((size_t)CAH * CFE);
    bf16_t* h2att_wT_b  = alloc_bf((size_t)CAH * CH);
    bf16_t* cls_wT_b    = alloc_bf((size_t)CVP * CH);
    bf16_t* fc_feats_b  = alloc_bf((size_t)CB * CFEAT);
    bf16_t* att_feats_b = alloc_bf((size_t)CB * CNREG * CFEAT);
    bf16_t* att_e_b     = alloc_bf((size_t)CB * CNREG * CFE);
    bf16_t* w_all       = alloc_bf((size_t)(CT - 1) * CB * 1024);
    bf16_t* xba         = alloc_bf((size_t)CB * XBA);       // [h_lang | fc_e]
    bf16_t* x_lang      = alloc_bf((size_t)CB * XLG);       // [att_res | h_att]
    bf16_t* h_all       = alloc_bf((size_t)CB * (CT - 1) * CH);
    float*  p_att       = alloc_f ((size_t)CB * CNREG * CAH);
    float*  h_att_f     = alloc_f ((size_t)CB * CH);
    float*  cbias_att   = alloc_f (G4);
    float*  cbias_lang  = alloc_f (G4);
    float*  c_att       = alloc_f ((size_t)CB * CH);
    float*  c_lang      = alloc_f ((size_t)CB * CH);

    // ---- zero state ----
    hipMemsetAsync(xba,    0, (size_t)CB * XBA * 2, stream);
    hipMemsetAsync(x_lang, 0, (size_t)CB * XLG * 2, stream);
    hipMemsetAsync(c_att,  0, (size_t)CB * CH * 4, stream);
    hipMemsetAsync(c_lang, 0, (size_t)CB * CH * 4, stream);
    hipMemsetAsync(cls_wT_b + (size_t)CV * CH, 0, (size_t)(CVP - CV) * CH * 2, stream);

    const dim3 blk(256);
    auto mk = [](const bf16_t* A, int lda, const bf16_t* W, int ldw, int kt) {
        return Seg{A, W, lda, ldw, kt};
    };
    const Seg zs{nullptr, nullptr, 0, 0, 0};

    // ---- one-time conversions ----
    convert_perm<<<dim3(12, G4), blk, 0, stream>>>(attl_wih, attl_wih_p, 3048, 3072);
    convert_perm<<<dim3(4,  G4), blk, 0, stream>>>(attl_whh, attl_whh_p, CH, CH);
    convert_perm<<<dim3(8,  G4), blk, 0, stream>>>(langl_wih, langl_wih_p, 2048, 2048);
    convert_perm<<<dim3(4,  G4), blk, 0, stream>>>(langl_whh, langl_whh_p, CH, CH);
    bias_perm<<<16, blk, 0, stream>>>(attl_bih, attl_bhh, cbias_att);
    bias_perm<<<16, blk, 0, stream>>>(langl_bih, langl_bhh, cbias_lang);
    convert_pad<<<dim3(8,  CB), blk, 0, stream>>>(fc_feats, fc_feats_b, CFEAT, CFEAT);
    convert_pad<<<dim3(8,  CB * CNREG), blk, 0, stream>>>(att_feats, att_feats_b, CFEAT, CFEAT);
    transpose_convert<<<dim3(CFE/32, CFEAT/32), blk, 0, stream>>>(fc_w,    fc_wT_b,    CFEAT, CFE);
    transpose_convert<<<dim3(CFE/32, CFEAT/32), blk, 0, stream>>>(atte_w,  atte_wT_b,  CFEAT, CFE);
    transpose_convert<<<dim3(CAH/32, CFE/32),   blk, 0, stream>>>(ctx_w,   ctx_wT_b,   CFE,   CAH);
    transpose_convert<<<dim3(CAH/32, CH/32),    blk, 0, stream>>>(h2att_w, h2att_wT_b, CH,    CAH);
    transpose_convert<<<dim3(CDIV(CV,32), CH/32), blk, 0, stream>>>(cls_w, cls_wT_b,   CH,    CV);
    emb_all<<<dim3(4, (CT - 1) * CB), blk, 0, stream>>>(emb_w, captions, w_all);

    // ---- preamble GEMMs (MODE2: A-panel clustered per XCD; A >> W) ----
    gemm3<true,true,2><<<16, blk, 0, stream>>>(
        mk(fc_feats_b, CFEAT, fc_wT_b, CFEAT, 32), 16, fc_b, xba + CH, XBA, 1 << 30);
    gemm3<true,true,2><<<576, blk, 0, stream>>>(
        mk(att_feats_b, CFEAT, atte_wT_b, CFEAT, 32), 16, atte_b, att_e_b, CFE, 1 << 30);
    gemm3<false,false,2><<<288, blk, 0, stream>>>(
        mk(att_e_b, CFE, ctx_wT_b, CFE, 16), 8, ctx_b, p_att, CAH, 1 << 30);

    // ---- recurrence: 3 launches per step ----
    for (int t = 0; t < CT - 1; ++t) {
        // att-LSTM: K = [h_lang|fc_e](2048) ++ w_t(1024) ++ h_att(1024); kt in BK=128 units
        gate_lstm<3><<<dim3(256, 2), blk, 0, stream>>>(
            mk(xba, XBA, attl_wih_p, 3072, 16),
            mk(w_all + (size_t)t * CB * 1024, 1024, attl_wih_p + 2048, 3072, 8),
            mk(x_lang + CH, XLG, attl_whh_p, CH, 8),
            cbias_att, c_att,
            x_lang + CH, XLG,        // h_att bf16 (also next step's seg2 input)
            nullptr, 0,
            h_att_f);                // h_att fp32 for attention

        attn_k<<<CB, blk, 0, stream>>>(
            p_att, h_att_f, h2att_wT_b, h2att_b, att_e_b, alpha_w, alpha_b, x_lang);

        // lang-LSTM: K = [att_res|h_att](2048) ++ h_lang(1024)
        gate_lstm<2><<<dim3(256, 2), blk, 0, stream>>>(
            mk(x_lang, XLG, langl_wih_p, 2048, 16),
            mk(xba, XBA, langl_whh_p, CH, 8),
            zs,
            cbias_lang, c_lang,
            xba, XBA,                         // h_lang bf16 (next step input)
            h_all + (size_t)t * CH, 16384,    // h_all[b][t][:] (row stride 16*1024)
            nullptr);
    }

    // ---- deferred classifier: [2048,1024] @ W^T -> out (cols < 12000) ----
    gemm3<false,false,1><<<(CVP/64) * (2048/128), blk, 0, stream>>>(
        mk(h_all, CH, cls_wT_b, CH, 16), 16, cls_b, out, CV, CV);

    logsoftmax_inplace<<<2048, blk, 0, stream>>>(out);
}

// Round 8
// 3803.705 us; speedup vs baseline: 3.4084x; 1.0658x over previous
//
#include <hip/hip_runtime.h>
#include <cstddef>
#include <cstdint>

// ---------------- problem constants ----------------
constexpr int CV    = 12000;
constexpr int CVP   = 12032;
constexpr int CWE   = 1000;
constexpr int CFEAT = 2048;
constexpr int CFE   = 1024;
constexpr int CH    = 1024;
constexpr int CAH   = 512;
constexpr int CNREG = 36;
constexpr int CB    = 128;
constexpr int CT    = 17;
constexpr int XBA   = 2048;    // xba = [h_lang | fc_e]
constexpr int XLG   = 2048;    // x_lang = [att_res | h_att]
constexpr int G4    = 4096;

#define CDIV(a,b) (((a)+(b)-1)/(b))

typedef __bf16 bf16_t;
typedef __bf16 bf16x8 __attribute__((ext_vector_type(8)));
typedef float  f32x4  __attribute__((ext_vector_type(4)));

struct Seg { const bf16_t* A; const bf16_t* W; int lda, ldw, kt; };

// =======================================================================
// pre_gemm: preamble GEMM. C = A @ W^T + b. BM=128, BN=64, BK=64.
// 1D grid, n-slow XCD swizzle (W slice resident per XCD; A streams via L3).
// Single-barrier pipelined K-loop.
// =======================================================================
template<bool RELU, bool OUTBF>
__global__ __launch_bounds__(256)
void pre_gemm(Seg s0, int inner, const float* __restrict__ bias1,
              void* __restrict__ Cout, int ldc)
{
    const int tid = threadIdx.x;
    const int wid = tid >> 6, lane = tid & 63;
    const int wr = wid >> 1, wc = wid & 1;
    const int llo = lane & 15, lhi = lane >> 4;
    const int nb = gridDim.x, id = blockIdx.x;
    const int sw = (id & 7) * (nb >> 3) + (id >> 3);   // nb % 8 == 0
    const int n0 = (sw / inner) * 64;
    const int m0 = (sw % inner) * 128;

    __shared__ __align__(16) uint8_t sm[2][24576];  // A [0,16384) | B [16384,24576)

    const int TT = s0.kt;
    f32x4 acc[4][2] = {};
    uint4 ra[4], rb[2];
    const int srow = tid >> 3, sc = tid & 7;
    const int cswz = (sc ^ (srow & 7)) << 4;

    auto load_tile = [&](int ti) {
        const int k0 = ti << 6;
        #pragma unroll
        for (int i = 0; i < 4; ++i)
            ra[i] = *(const uint4*)(s0.A + (size_t)(m0 + i * 32 + srow) * s0.lda + k0 + sc * 8);
        #pragma unroll
        for (int i = 0; i < 2; ++i)
            rb[i] = *(const uint4*)(s0.W + (size_t)(n0 + i * 32 + srow) * s0.ldw + k0 + sc * 8);
    };
    auto write_tile = [&](int buf) {
        uint8_t* base = sm[buf];
        #pragma unroll
        for (int i = 0; i < 4; ++i) *(uint4*)(base + (i * 32 + srow) * 128 + cswz) = ra[i];
        #pragma unroll
        for (int i = 0; i < 2; ++i) *(uint4*)(base + 16384 + (i * 32 + srow) * 128 + cswz) = rb[i];
    };
    auto compute = [&](int buf) {
        const uint8_t* base = sm[buf];
        const int r7 = llo & 7;
        #pragma unroll
        for (int kk = 0; kk < 2; ++kk) {
            const int coff = ((kk * 4 + lhi) ^ r7) << 4;
            bf16x8 af[4], bg[2];
            #pragma unroll
            for (int fm = 0; fm < 4; ++fm)
                af[fm] = *(const bf16x8*)(base + (wr * 64 + fm * 16 + llo) * 128 + coff);
            #pragma unroll
            for (int fn = 0; fn < 2; ++fn)
                bg[fn] = *(const bf16x8*)(base + 16384 + (wc * 32 + fn * 16 + llo) * 128 + coff);
            #pragma unroll
            for (int fm = 0; fm < 4; ++fm)
                #pragma unroll
                for (int fn = 0; fn < 2; ++fn)
                    acc[fm][fn] = __builtin_amdgcn_mfma_f32_16x16x32_bf16(
                        af[fm], bg[fn], acc[fm][fn], 0, 0, 0);
        }
    };

    // single-barrier pipelined main loop
    load_tile(0); write_tile(0);
    load_tile(1);                 // TT >= 2 always here
    __syncthreads();
    int cur = 0;
    for (int ti = 0; ti < TT; ++ti) {
        if (ti + 1 < TT) write_tile(cur ^ 1);
        if (ti + 2 < TT) load_tile(ti + 2);
        compute(cur);
        __syncthreads();
        cur ^= 1;
    }

    const int colb = n0 + wc * 32;
    const int rowb = m0 + wr * 64 + lhi * 4;
    #pragma unroll
    for (int fn = 0; fn < 2; ++fn) {
        const int col = colb + fn * 16 + llo;
        const float b = bias1 ? bias1[col] : 0.f;
        #pragma unroll
        for (int fm = 0; fm < 4; ++fm)
            #pragma unroll
            for (int r = 0; r < 4; ++r) {
                float v = acc[fm][fn][r] + b;
                if (RELU) v = fmaxf(v, 0.f);
                const size_t off = (size_t)(rowb + fm * 16 + r) * ldc + col;
                if (OUTBF) ((bf16_t*)Cout)[off] = (bf16_t)v;
                else       ((float*) Cout)[off] = v;
            }
    }
}

// =======================================================================
// cls_gemm: classifier. A[2048,1024] @ W[12032,1024]^T + b -> out fp32
// (ldc = CV, cols clipped at CV). BM=128, BN=128, BK=64, 4 waves 2x2,
// wave 64x64. Per-wave row stores are 256 B contiguous (full L2 lines).
// Grid 1504, n-slow XCD swizzle (inner = 16 m-tiles).
// =======================================================================
__global__ __launch_bounds__(256)
void cls_gemm(const bf16_t* __restrict__ A, const bf16_t* __restrict__ W,
              const float* __restrict__ bias, float* __restrict__ C)
{
    const int tid = threadIdx.x;
    const int wid = tid >> 6, lane = tid & 63;
    const int wr = wid >> 1, wc = wid & 1;
    const int llo = lane & 15, lhi = lane >> 4;
    const int nb = gridDim.x, id = blockIdx.x;
    const int sw = (id & 7) * (nb >> 3) + (id >> 3);
    const int n0 = (sw / 16) * 128;
    const int m0 = (sw % 16) * 128;

    __shared__ __align__(16) uint8_t smA[2][16384];
    __shared__ __align__(16) uint8_t smB[2][16384];

    constexpr int TT = 16;   // K = 1024, BK = 64
    f32x4 acc[4][4] = {};
    uint4 ra[4], rbv[4];

    auto load_tile = [&](int ti) {
        const int k0 = ti << 6;
        #pragma unroll
        for (int i = 0; i < 4; ++i) {
            const int q = tid + i * 256;          // 0..1023
            const int row = q >> 3, c = q & 7;
            ra[i]  = *(const uint4*)(A + (size_t)(m0 + row) * CH + k0 + c * 8);
            rbv[i] = *(const uint4*)(W + (size_t)(n0 + row) * CH + k0 + c * 8);
        }
    };
    auto write_tile = [&](int buf) {
        #pragma unroll
        for (int i = 0; i < 4; ++i) {
            const int q = tid + i * 256;
            const int row = q >> 3, c = q & 7;
            const int o = row * 128 + ((c ^ (row & 7)) << 4);
            *(uint4*)(smA[buf] + o) = ra[i];
            *(uint4*)(smB[buf] + o) = rbv[i];
        }
    };
    auto compute = [&](int buf) {
        const int r7 = llo & 7;
        #pragma unroll
        for (int kk = 0; kk < 2; ++kk) {
            const int coff = ((kk * 4 + lhi) ^ r7) << 4;
            bf16x8 af[4], bg[4];
            #pragma unroll
            for (int fm = 0; fm < 4; ++fm)
                af[fm] = *(const bf16x8*)(smA[buf] + (wr * 64 + fm * 16 + llo) * 128 + coff);
            #pragma unroll
            for (int fn = 0; fn < 4; ++fn)
                bg[fn] = *(const bf16x8*)(smB[buf] + (wc * 64 + fn * 16 + llo) * 128 + coff);
            #pragma unroll
            for (int fm = 0; fm < 4; ++fm)
                #pragma unroll
                for (int fn = 0; fn < 4; ++fn)
                    acc[fm][fn] = __builtin_amdgcn_mfma_f32_16x16x32_bf16(
                        af[fm], bg[fn], acc[fm][fn], 0, 0, 0);
        }
    };

    load_tile(0); write_tile(0);
    load_tile(1);
    __syncthreads();
    int cur = 0;
    for (int ti = 0; ti < TT; ++ti) {
        if (ti + 1 < TT) write_tile(cur ^ 1);
        if (ti + 2 < TT) load_tile(ti + 2);
        compute(cur);
        __syncthreads();
        cur ^= 1;
    }

    #pragma unroll
    for (int fn = 0; fn < 4; ++fn) {
        const int col = n0 + wc * 64 + fn * 16 + llo;
        if (col >= CV) continue;
        const float b = bias[col];
        #pragma unroll
        for (int fm = 0; fm < 4; ++fm)
            #pragma unroll
            for (int r = 0; r < 4; ++r) {
                const int row = m0 + wr * 64 + fm * 16 + lhi * 4 + r;
                C[(size_t)row * CV + col] = acc[fm][fn][r] + b;
            }
    }
}

// =======================================================================
// gate_lstm: full-K gate GEMM with fused LSTM epilogue.
// Weights pre-permuted: row r' = 4*j + gate. Tile 64x16, grid (256, 2),
// BK=128, single-barrier pipelined double-buffered LDS.
// =======================================================================
template<int NSEG>
__global__ __launch_bounds__(256)
void gate_lstm(Seg s0, Seg s1, Seg s2, const float* __restrict__ cbias,
               float* __restrict__ cstate,
               bf16_t* __restrict__ hdst1, int ld1,
               bf16_t* __restrict__ hdst2, int ld2,
               float* __restrict__ hdst3)
{
    const int tid = threadIdx.x;
    const int w = tid >> 6, lane = tid & 63;
    const int llo = lane & 15, lhi = lane >> 4;
    const int nt = blockIdx.x;
    const int m0 = blockIdx.y * 64;
    const int n0 = nt * 16;

    __shared__ __align__(16) uint8_t smA[2][16384];   // 64 rows x 256B
    __shared__ __align__(16) uint8_t smB[2][4096];    // 16 rows x 256B

    const int TT = s0.kt + (NSEG > 1 ? s1.kt : 0) + (NSEG > 2 ? s2.kt : 0);
    f32x4 acc = {0.f, 0.f, 0.f, 0.f};
    uint4 ra[4], rb;

    auto load_tile = [&](int ti) {
        const bf16_t* As = s0.A; const bf16_t* Ws = s0.W;
        int la = s0.lda, lw = s0.ldw, rt = ti;
        if (NSEG > 1 && rt >= s0.kt) {
            rt -= s0.kt; As = s1.A; Ws = s1.W; la = s1.lda; lw = s1.ldw;
            if (NSEG > 2 && rt >= s1.kt) {
                rt -= s1.kt; As = s2.A; Ws = s2.W; la = s2.lda; lw = s2.ldw;
            }
        }
        const int k0 = rt << 7;    // BK = 128
        #pragma unroll
        for (int i = 0; i < 4; ++i) {
            const int q = tid + i * 256;
            const int row = q >> 4, c = q & 15;
            ra[i] = *(const uint4*)(As + (size_t)(m0 + row) * la + k0 + c * 8);
        }
        {
            const int row = tid >> 4, c = tid & 15;
            rb = *(const uint4*)(Ws + (size_t)(n0 + row) * lw + k0 + c * 8);
        }
    };
    auto write_tile = [&](int buf) {
        #pragma unroll
        for (int i = 0; i < 4; ++i) {
            const int q = tid + i * 256;
            const int row = q >> 4, c = q & 15;
            *(uint4*)(smA[buf] + row * 256 + ((c ^ (row & 7)) << 4)) = ra[i];
        }
        {
            const int row = tid >> 4, c = tid & 15;
            *(uint4*)(smB[buf] + row * 256 + ((c ^ (row & 7)) << 4)) = rb;
        }
    };
    auto compute = [&](int buf) {
        const int r7 = llo & 7;
        #pragma unroll
        for (int kk = 0; kk < 4; ++kk) {
            const int coff = ((kk * 4 + lhi) ^ r7) << 4;
            bf16x8 a  = *(const bf16x8*)(smA[buf] + (w * 16 + llo) * 256 + coff);
            bf16x8 bb = *(const bf16x8*)(smB[buf] + llo * 256 + coff);
            acc = __builtin_amdgcn_mfma_f32_16x16x32_bf16(a, bb, acc, 0, 0, 0);
        }
    };

    load_tile(0); write_tile(0);
    load_tile(1);
    __syncthreads();
    int cur = 0;
    for (int ti = 0; ti < TT; ++ti) {
        if (ti + 1 < TT) write_tile(cur ^ 1);
        if (ti + 2 < TT) load_tile(ti + 2);
        compute(cur);
        __syncthreads();
        cur ^= 1;
    }

    // ---- LSTM epilogue ----
    const int gate = llo & 3;
    const int jg   = nt * 4 + (llo >> 2);
    const float bsum = cbias[n0 + llo];
    const int base = lane & ~3;
    const int rowb = m0 + w * 16 + lhi * 4;
    #pragma unroll
    for (int r = 0; r < 4; ++r) {
        const float v  = acc[r] + bsum;
        const float gi = __shfl(v, base + 0);
        const float gf = __shfl(v, base + 1);
        const float gg = __shfl(v, base + 2);
        const float go = __shfl(v, base + 3);
        const int b = rowb + r;
        const float cold = cstate[b * CH + jg];
        const float si = 1.f / (1.f + expf(-gi));
        const float sf = 1.f / (1.f + expf(-gf));
        const float so = 1.f / (1.f + expf(-go));
        const float cn = sf * cold + si * tanhf(gg);
        const float hn = so * tanhf(cn);
        if (gate == 0)      hdst1[(size_t)b * ld1 + jg] = (bf16_t)hn;
        else if (gate == 1) { if (hdst2) hdst2[(size_t)b * ld2 + jg] = (bf16_t)hn; }
        else if (gate == 2) cstate[b * CH + jg] = cn;
        else                { if (hdst3) hdst3[b * CH + jg] = hn; }
    }
}

// ---------------- attention: hq + e + softmax + weighted sum ----------------
__global__ __launch_bounds__(256)
void attn_k(const float* __restrict__ p_att, const float* __restrict__ h_att_f,
            const bf16_t* __restrict__ h2att_wT, const float* __restrict__ h2att_b,
            const bf16_t* __restrict__ att_e, const float* __restrict__ alpha_w,
            const float* __restrict__ alpha_b, bf16_t* __restrict__ x_lang)
{
    __shared__ float sh[CH];
    __shared__ float shq[CAH];
    __shared__ float se[CNREG], salpha[CNREG];
    const int b = blockIdx.x, tid = threadIdx.x;

    for (int j = tid; j < CH; j += 256) sh[j] = h_att_f[b * CH + j];
    __syncthreads();

    for (int n = tid; n < CAH; n += 256) {
        const bf16_t* wrow = h2att_wT + (size_t)n * CH;
        float s = 0.f;
        for (int k = 0; k < CH; k += 8) {
            bf16x8 w8 = *(const bf16x8*)(wrow + k);
            #pragma unroll
            for (int q = 0; q < 8; ++q) s = fmaf((float)w8[q], sh[k + q], s);
        }
        shq[n] = s + h2att_b[n];
    }
    __syncthreads();

    const int wave = tid >> 6, lane = tid & 63;
    for (int n = wave; n < CNREG; n += 4) {
        const float* pr = p_att + ((size_t)b * CNREG + n) * CAH;
        float s = 0.f;
        #pragma unroll
        for (int q = 0; q < CAH / 64; ++q) {
            const int d = lane + q * 64;
            s += alpha_w[d] * tanhf(pr[d] + shq[d]);
        }
        for (int off = 32; off; off >>= 1) s += __shfl_down(s, off);
        if (lane == 0) se[n] = s + alpha_b[0];
    }
    __syncthreads();

    float mx = -1e30f;
    for (int n = 0; n < CNREG; ++n) mx = fmaxf(mx, se[n]);
    float sum = 0.f;
    for (int n = 0; n < CNREG; ++n) sum += expf(se[n] - mx);
    if (tid < CNREG) salpha[tid] = expf(se[tid] - mx) / sum;
    __syncthreads();

    for (int d = tid; d < CFE; d += 256) {
        float s = 0.f;
        const bf16_t* ae = att_e + (size_t)b * CNREG * CFE + d;
        #pragma unroll 4
        for (int n = 0; n < CNREG; ++n) s = fmaf(salpha[n], (float)ae[(size_t)n * CFE], s);
        x_lang[(size_t)b * XLG + d] = (bf16_t)s;
    }
}

// ---------------- prep kernels ----------------
__global__ void convert_pad(const float* __restrict__ src, bf16_t* __restrict__ dst,
                            int C, int Cp)
{
    const int r = blockIdx.y;
    const int c = blockIdx.x * 256 + threadIdx.x;
    if (c >= Cp) return;
    dst[(size_t)r * Cp + c] = (c < C) ? (bf16_t)src[(size_t)r * C + c] : (bf16_t)0.f;
}

// gate-interleave row permutation: dst row r' = src row (r'&3)*1024 + (r'>>2)
__global__ void convert_perm(const float* __restrict__ src, bf16_t* __restrict__ dst,
                             int C, int Cp)
{
    const int rp = blockIdx.y;
    const int c = blockIdx.x * 256 + threadIdx.x;
    if (c >= Cp) return;
    const int rs = (rp & 3) * 1024 + (rp >> 2);
    dst[(size_t)rp * Cp + c] = (c < C) ? (bf16_t)src[(size_t)rs * C + c] : (bf16_t)0.f;
}

__global__ void bias_perm(const float* __restrict__ bih, const float* __restrict__ bhh,
                          float* __restrict__ dst)
{
    const int rp = blockIdx.x * 256 + threadIdx.x;
    if (rp >= G4) return;
    const int rs = (rp & 3) * 1024 + (rp >> 2);
    dst[rp] = bih[rs] + bhh[rs];
}

__global__ __launch_bounds__(256)
void transpose_convert(const float* __restrict__ src, bf16_t* __restrict__ dst,
                       int K, int N)
{
    __shared__ float tile[32][33];
    const int n0 = blockIdx.x * 32, k0 = blockIdx.y * 32;
    const int tx = threadIdx.x & 31, ty = threadIdx.x >> 5;   // 32 x 8
    #pragma unroll
    for (int i = 0; i < 4; ++i) {
        const int k = k0 + ty + i * 8, n = n0 + tx;
        tile[ty + i * 8][tx] = (k < K && n < N) ? src[(size_t)k * N + n] : 0.f;
    }
    __syncthreads();
    #pragma unroll
    for (int i = 0; i < 4; ++i) {
        const int n = n0 + ty + i * 8, k = k0 + tx;
        if (n < N && k < K) dst[(size_t)n * K + k] = (bf16_t)tile[tx][ty + i * 8];
    }
}

__global__ void emb_all(const float* __restrict__ emb_w,
                        const int* __restrict__ captions, bf16_t* __restrict__ w_all)
{
    const int r = blockIdx.y;                       // t*128 + b
    const int j = blockIdx.x * 256 + threadIdx.x;   // 0..1023
    const int t = r >> 7, b = r & 127;
    const int tok = captions[b * CT + t];
    const float v = (j < CWE) ? fmaxf(emb_w[(size_t)tok * CWE + j], 0.f) : 0.f;
    w_all[(size_t)r * 1024 + j] = (bf16_t)v;
}

// ---- in-place log-softmax over each of 2048 rows of out (length 12000) ----
__global__ __launch_bounds__(256)
void logsoftmax_inplace(float* __restrict__ out)
{
    __shared__ float red[4];
    const int r = blockIdx.x, tid = threadIdx.x;
    float* row = out + (size_t)r * CV;
    constexpr int NI = 47;

    float v[NI];
    float mx = -1e30f;
    #pragma unroll
    for (int i = 0; i < NI; ++i) {
        const int j = tid + i * 256;
        v[i] = (j < CV) ? row[j] : -1e30f;
        mx = fmaxf(mx, v[i]);
    }
    for (int off = 32; off; off >>= 1) mx = fmaxf(mx, __shfl_down(mx, off));
    if ((tid & 63) == 0) red[tid >> 6] = mx;
    __syncthreads();
    mx = fmaxf(fmaxf(red[0], red[1]), fmaxf(red[2], red[3]));
    __syncthreads();

    float sum = 0.f;
    #pragma unroll
    for (int i = 0; i < NI; ++i)
        if (tid + i * 256 < CV) sum += expf(v[i] - mx);
    for (int off = 32; off; off >>= 1) sum += __shfl_down(sum, off);
    if ((tid & 63) == 0) red[tid >> 6] = sum;
    __syncthreads();
    sum = red[0] + red[1] + red[2] + red[3];
    const float lse = mx + logf(sum);

    #pragma unroll
    for (int i = 0; i < NI; ++i) {
        const int j = tid + i * 256;
        if (j < CV) row[j] = v[i] - lse;
    }
}

// ---------------- launch ----------------
extern "C" void kernel_launch(void* const* d_in, const int* in_sizes, int n_in,
                              void* d_out, int out_size, void* d_ws, size_t ws_size,
                              hipStream_t stream)
{
    const float* fc_feats  = (const float*)d_in[0];
    const float* att_feats = (const float*)d_in[1];
    const int*   captions  = (const int*)  d_in[2];
    const float* emb_w     = (const float*)d_in[3];
    const float* fc_w      = (const float*)d_in[4];
    const float* fc_b      = (const float*)d_in[5];
    const float* atte_w    = (const float*)d_in[6];
    const float* atte_b    = (const float*)d_in[7];
    const float* ctx_w     = (const float*)d_in[8];
    const float* ctx_b     = (const float*)d_in[9];
    const float* attl_wih  = (const float*)d_in[10];
    const float* attl_whh  = (const float*)d_in[11];
    const float* attl_bih  = (const float*)d_in[12];
    const float* attl_bhh  = (const float*)d_in[13];
    const float* h2att_w   = (const float*)d_in[14];
    const float* h2att_b   = (const float*)d_in[15];
    const float* alpha_w   = (const float*)d_in[16];
    const float* alpha_b   = (const float*)d_in[17];
    const float* langl_wih = (const float*)d_in[18];
    const float* langl_whh = (const float*)d_in[19];
    const float* langl_bih = (const float*)d_in[20];
    const float* langl_bhh = (const float*)d_in[21];
    const float* cls_w     = (const float*)d_in[22];
    const float* cls_b     = (const float*)d_in[23];

    float* out = (float*)d_out;

    // ---- workspace layout ----
    char* p = (char*)d_ws;
    auto alloc_bf = [&](size_t e) { bf16_t* q = (bf16_t*)p; p += e * 2; return q; };
    auto alloc_f  = [&](size_t e) { float*  q = (float*) p; p += e * 4; return q; };

    bf16_t* attl_wih_p  = alloc_bf((size_t)G4 * 3072);
    bf16_t* attl_whh_p  = alloc_bf((size_t)G4 * CH);
    bf16_t* langl_wih_p = alloc_bf((size_t)G4 * 2048);
    bf16_t* langl_whh_p = alloc_bf((size_t)G4 * CH);
    bf16_t* fc_wT_b     = alloc_bf((size_t)CFE * CFEAT);
    bf16_t* atte_wT_b   = alloc_bf((size_t)CFE * CFEAT);
    bf16_t* ctx_wT_b    = alloc_bf((size_t)CAH * CFE);
    bf16_t* h2att_wT_b  = alloc_bf((size_t)CAH * CH);
    bf16_t* cls_wT_b    = alloc_bf((size_t)CVP * CH);
    bf16_t* fc_feats_b  = alloc_bf((size_t)CB * CFEAT);
    bf16_t* att_feats_b = alloc_bf((size_t)CB * CNREG * CFEAT);
    bf16_t* att_e_b     = alloc_bf((size_t)CB * CNREG * CFE);
    bf16_t* w_all       = alloc_bf((size_t)(CT - 1) * CB * 1024);
    bf16_t* xba         = alloc_bf((size_t)CB * XBA);
    bf16_t* x_lang      = alloc_bf((size_t)CB * XLG);
    bf16_t* h_all       = alloc_bf((size_t)CB * (CT - 1) * CH);
    float*  p_att       = alloc_f ((size_t)CB * CNREG * CAH);
    float*  h_att_f     = alloc_f ((size_t)CB * CH);
    float*  cbias_att   = alloc_f (G4);
    float*  cbias_lang  = alloc_f (G4);
    float*  c_att       = alloc_f ((size_t)CB * CH);
    float*  c_lang      = alloc_f ((size_t)CB * CH);

    // ---- zero state ----
    hipMemsetAsync(xba,    0, (size_t)CB * XBA * 2, stream);
    hipMemsetAsync(x_lang, 0, (size_t)CB * XLG * 2, stream);
    hipMemsetAsync(c_att,  0, (size_t)CB * CH * 4, stream);
    hipMemsetAsync(c_lang, 0, (size_t)CB * CH * 4, stream);
    hipMemsetAsync(cls_wT_b + (size_t)CV * CH, 0, (size_t)(CVP - CV) * CH * 2, stream);

    const dim3 blk(256);
    auto mk = [](const bf16_t* A, int lda, const bf16_t* W, int ldw, int kt) {
        return Seg{A, W, lda, ldw, kt};
    };
    const Seg zs{nullptr, nullptr, 0, 0, 0};

    // ---- one-time conversions ----
    convert_perm<<<dim3(12, G4), blk, 0, stream>>>(attl_wih, attl_wih_p, 3048, 3072);
    convert_perm<<<dim3(4,  G4), blk, 0, stream>>>(attl_whh, attl_whh_p, CH, CH);
    convert_perm<<<dim3(8,  G4), blk, 0, stream>>>(langl_wih, langl_wih_p, 2048, 2048);
    convert_perm<<<dim3(4,  G4), blk, 0, stream>>>(langl_whh, langl_whh_p, CH, CH);
    bias_perm<<<16, blk, 0, stream>>>(attl_bih, attl_bhh, cbias_att);
    bias_perm<<<16, blk, 0, stream>>>(langl_bih, langl_bhh, cbias_lang);
    convert_pad<<<dim3(8,  CB), blk, 0, stream>>>(fc_feats, fc_feats_b, CFEAT, CFEAT);
    convert_pad<<<dim3(8,  CB * CNREG), blk, 0, stream>>>(att_feats, att_feats_b, CFEAT, CFEAT);
    transpose_convert<<<dim3(CFE/32, CFEAT/32), blk, 0, stream>>>(fc_w,    fc_wT_b,    CFEAT, CFE);
    transpose_convert<<<dim3(CFE/32, CFEAT/32), blk, 0, stream>>>(atte_w,  atte_wT_b,  CFEAT, CFE);
    transpose_convert<<<dim3(CAH/32, CFE/32),   blk, 0, stream>>>(ctx_w,   ctx_wT_b,   CFE,   CAH);
    transpose_convert<<<dim3(CAH/32, CH/32),    blk, 0, stream>>>(h2att_w, h2att_wT_b, CH,    CAH);
    transpose_convert<<<dim3(CDIV(CV,32), CH/32), blk, 0, stream>>>(cls_w, cls_wT_b,   CH,    CV);
    emb_all<<<dim3(4, (CT - 1) * CB), blk, 0, stream>>>(emb_w, captions, w_all);

    // ---- preamble GEMMs (n-slow swizzle: W slice resident per XCD) ----
    pre_gemm<true,true><<<16, blk, 0, stream>>>(
        mk(fc_feats_b, CFEAT, fc_wT_b, CFEAT, 32), 1, fc_b, xba + CH, XBA);
    pre_gemm<true,true><<<576, blk, 0, stream>>>(
        mk(att_feats_b, CFEAT, atte_wT_b, CFEAT, 32), 36, atte_b, att_e_b, CFE);
    pre_gemm<false,false><<<288, blk, 0, stream>>>(
        mk(att_e_b, CFE, ctx_wT_b, CFE, 16), 36, ctx_b, p_att, CAH);

    // ---- recurrence: 3 launches per step ----
    for (int t = 0; t < CT - 1; ++t) {
        gate_lstm<3><<<dim3(256, 2), blk, 0, stream>>>(
            mk(xba, XBA, attl_wih_p, 3072, 16),
            mk(w_all + (size_t)t * CB * 1024, 1024, attl_wih_p + 2048, 3072, 8),
            mk(x_lang + CH, XLG, attl_whh_p, CH, 8),
            cbias_att, c_att,
            x_lang + CH, XLG,
            nullptr, 0,
            h_att_f);

        attn_k<<<CB, blk, 0, stream>>>(
            p_att, h_att_f, h2att_wT_b, h2att_b, att_e_b, alpha_w, alpha_b, x_lang);

        gate_lstm<2><<<dim3(256, 2), blk, 0, stream>>>(
            mk(x_lang, XLG, langl_wih_p, 2048, 16),
            mk(xba, XBA, langl_whh_p, CH, 8),
            zs,
            cbias_lang, c_lang,
            xba, XBA,
            h_all + (size_t)t * CH, 16384,
            nullptr);
    }

    // ---- deferred classifier: [2048,1024] @ W^T -> out (cols < 12000) ----
    cls_gemm<<<1504, blk, 0, stream>>>(h_all, cls_wT_b, cls_b, out);

    logsoftmax_inplace<<<2048, blk, 0, stream>>>(out);
}

// Round 9
// 3455.910 us; speedup vs baseline: 3.7514x; 1.1006x over previous
//
#include <hip/hip_runtime.h>
#include <cstddef>
#include <cstdint>

// ---------------- problem constants ----------------
constexpr int CV    = 12000;
constexpr int CVP   = 12032;
constexpr int CWE   = 1000;
constexpr int CFEAT = 2048;
constexpr int CFE   = 1024;
constexpr int CH    = 1024;
constexpr int CAH   = 512;
constexpr int CNREG = 36;
constexpr int CB    = 128;
constexpr int CT    = 17;
constexpr int G4    = 4096;
constexpr int XH    = 2048;    // xh  = [h_lang | h_att]
constexpr int XL3   = 3072;    // xl3 = [att_res | h_att | h_lang_prev]

#define CDIV(a,b) (((a)+(b)-1)/(b))

typedef __bf16 bf16_t;
typedef __bf16 bf16x8 __attribute__((ext_vector_type(8)));
typedef __bf16 bf16x4 __attribute__((ext_vector_type(4)));
typedef float  f32x4  __attribute__((ext_vector_type(4)));

struct Seg { const bf16_t* A; const bf16_t* W; int lda, ldw, kt; };

// =======================================================================
// pre_gemm: C = A @ W^T + b. BM=128, BN=64, BK=64, n-slow XCD swizzle.
// =======================================================================
template<bool RELU, bool OUTBF>
__global__ __launch_bounds__(256)
void pre_gemm(Seg s0, int inner, const float* __restrict__ bias1,
              void* __restrict__ Cout, int ldc)
{
    const int tid = threadIdx.x;
    const int wid = tid >> 6, lane = tid & 63;
    const int wr = wid >> 1, wc = wid & 1;
    const int llo = lane & 15, lhi = lane >> 4;
    const int nb = gridDim.x, id = blockIdx.x;
    const int sw = (id & 7) * (nb >> 3) + (id >> 3);
    const int n0 = (sw / inner) * 64;
    const int m0 = (sw % inner) * 128;

    __shared__ __align__(16) uint8_t sm[2][24576];

    const int TT = s0.kt;
    f32x4 acc[4][2] = {};
    uint4 ra[4], rb[2];
    const int srow = tid >> 3, sc = tid & 7;
    const int cswz = (sc ^ (srow & 7)) << 4;

    auto load_tile = [&](int ti) {
        const int k0 = ti << 6;
        #pragma unroll
        for (int i = 0; i < 4; ++i)
            ra[i] = *(const uint4*)(s0.A + (size_t)(m0 + i * 32 + srow) * s0.lda + k0 + sc * 8);
        #pragma unroll
        for (int i = 0; i < 2; ++i)
            rb[i] = *(const uint4*)(s0.W + (size_t)(n0 + i * 32 + srow) * s0.ldw + k0 + sc * 8);
    };
    auto write_tile = [&](int buf) {
        uint8_t* base = sm[buf];
        #pragma unroll
        for (int i = 0; i < 4; ++i) *(uint4*)(base + (i * 32 + srow) * 128 + cswz) = ra[i];
        #pragma unroll
        for (int i = 0; i < 2; ++i) *(uint4*)(base + 16384 + (i * 32 + srow) * 128 + cswz) = rb[i];
    };
    auto compute = [&](int buf) {
        const uint8_t* base = sm[buf];
        const int r7 = llo & 7;
        #pragma unroll
        for (int kk = 0; kk < 2; ++kk) {
            const int coff = ((kk * 4 + lhi) ^ r7) << 4;
            bf16x8 af[4], bg[2];
            #pragma unroll
            for (int fm = 0; fm < 4; ++fm)
                af[fm] = *(const bf16x8*)(base + (wr * 64 + fm * 16 + llo) * 128 + coff);
            #pragma unroll
            for (int fn = 0; fn < 2; ++fn)
                bg[fn] = *(const bf16x8*)(base + 16384 + (wc * 32 + fn * 16 + llo) * 128 + coff);
            #pragma unroll
            for (int fm = 0; fm < 4; ++fm)
                #pragma unroll
                for (int fn = 0; fn < 2; ++fn)
                    acc[fm][fn] = __builtin_amdgcn_mfma_f32_16x16x32_bf16(
                        af[fm], bg[fn], acc[fm][fn], 0, 0, 0);
        }
    };

    load_tile(0); write_tile(0);
    load_tile(1);
    __syncthreads();
    int cur = 0;
    for (int ti = 0; ti < TT; ++ti) {
        if (ti + 1 < TT) write_tile(cur ^ 1);
        if (ti + 2 < TT) load_tile(ti + 2);
        compute(cur);
        __syncthreads();
        cur ^= 1;
    }

    const int colb = n0 + wc * 32;
    const int rowb = m0 + wr * 64 + lhi * 4;
    #pragma unroll
    for (int fn = 0; fn < 2; ++fn) {
        const int col = colb + fn * 16 + llo;
        const float b = bias1 ? bias1[col] : 0.f;
        #pragma unroll
        for (int fm = 0; fm < 4; ++fm)
            #pragma unroll
            for (int r = 0; r < 4; ++r) {
                float v = acc[fm][fn][r] + b;
                if (RELU) v = fmaxf(v, 0.f);
                const size_t off = (size_t)(rowb + fm * 16 + r) * ldc + col;
                if (OUTBF) ((bf16_t*)Cout)[off] = (bf16_t)v;
                else       ((float*) Cout)[off] = v;
            }
    }
}

// =======================================================================
// cls_gemm: A[2048,1024] @ W[12032,1024]^T + b -> out fp32 [2048, CV].
// BM=128, BN=128, BK=64. Epilogue staged in LDS for full-line stores.
// =======================================================================
__global__ __launch_bounds__(256)
void cls_gemm(const bf16_t* __restrict__ A, const bf16_t* __restrict__ W,
              const float* __restrict__ bias, float* __restrict__ C)
{
    const int tid = threadIdx.x;
    const int wid = tid >> 6, lane = tid & 63;
    const int wr = wid >> 1, wc = wid & 1;
    const int llo = lane & 15, lhi = lane >> 4;
    const int nb = gridDim.x, id = blockIdx.x;
    const int sw = (id & 7) * (nb >> 3) + (id >> 3);
    const int n0 = (sw / 16) * 128;
    const int m0 = (sw % 16) * 128;

    __shared__ __align__(16) uint8_t pool[65536];
    auto bufA = [&](int b) { return pool + b * 16384; };
    auto bufB = [&](int b) { return pool + 32768 + b * 16384; };

    constexpr int TT = 16;
    f32x4 acc[4][4] = {};
    uint4 ra[4], rbv[4];

    auto load_tile = [&](int ti) {
        const int k0 = ti << 6;
        #pragma unroll
        for (int i = 0; i < 4; ++i) {
            const int q = tid + i * 256;
            const int row = q >> 3, c = q & 7;
            ra[i]  = *(const uint4*)(A + (size_t)(m0 + row) * CH + k0 + c * 8);
            rbv[i] = *(const uint4*)(W + (size_t)(n0 + row) * CH + k0 + c * 8);
        }
    };
    auto write_tile = [&](int buf) {
        #pragma unroll
        for (int i = 0; i < 4; ++i) {
            const int q = tid + i * 256;
            const int row = q >> 3, c = q & 7;
            const int o = row * 128 + ((c ^ (row & 7)) << 4);
            *(uint4*)(bufA(buf) + o) = ra[i];
            *(uint4*)(bufB(buf) + o) = rbv[i];
        }
    };
    auto compute = [&](int buf) {
        const int r7 = llo & 7;
        #pragma unroll
        for (int kk = 0; kk < 2; ++kk) {
            const int coff = ((kk * 4 + lhi) ^ r7) << 4;
            bf16x8 af[4], bg[4];
            #pragma unroll
            for (int fm = 0; fm < 4; ++fm)
                af[fm] = *(const bf16x8*)(bufA(buf) + (wr * 64 + fm * 16 + llo) * 128 + coff);
            #pragma unroll
            for (int fn = 0; fn < 4; ++fn)
                bg[fn] = *(const bf16x8*)(bufB(buf) + (wc * 64 + fn * 16 + llo) * 128 + coff);
            #pragma unroll
            for (int fm = 0; fm < 4; ++fm)
                #pragma unroll
                for (int fn = 0; fn < 4; ++fn)
                    acc[fm][fn] = __builtin_amdgcn_mfma_f32_16x16x32_bf16(
                        af[fm], bg[fn], acc[fm][fn], 0, 0, 0);
        }
    };

    load_tile(0); write_tile(0);
    load_tile(1);
    __syncthreads();
    int cur = 0;
    for (int ti = 0; ti < TT; ++ti) {
        if (ti + 1 < TT) write_tile(cur ^ 1);
        if (ti + 2 < TT) load_tile(ti + 2);
        compute(cur);
        __syncthreads();
        cur ^= 1;
    }

    // ---- epilogue: stage 128x128 fp32 tile in LDS, store full 512B rows ----
    __syncthreads();
    float* reg = (float*)pool + (wr * 2 + wc) * 4096;   // 64x64 region per wave
    #pragma unroll
    for (int fn = 0; fn < 4; ++fn) {
        const int col = n0 + wc * 64 + fn * 16 + llo;
        const float b = (col < CV) ? bias[col] : 0.f;
        #pragma unroll
        for (int fm = 0; fm < 4; ++fm)
            #pragma unroll
            for (int r = 0; r < 4; ++r)
                reg[(fm * 16 + lhi * 4 + r) * 64 + fn * 16 + llo] = acc[fm][fn][r] + b;
    }
    __syncthreads();
    #pragma unroll
    for (int p = 0; p < 16; ++p) {
        const int r = p * 8 + (tid >> 5);
        const int colq = (tid & 31) * 4;
        if (n0 + colq >= CV) continue;
        const float* src = (float*)pool + ((r >> 6) * 2 + (colq >> 6)) * 4096
                         + (r & 63) * 64 + (colq & 63);
        float4 v = make_float4(src[0], src[1], src[2], src[3]);
        *(float4*)&C[(size_t)(m0 + r) * CV + n0 + colq] = v;
    }
}

// =======================================================================
// gate_lstm: single-segment gate GEMM + fused LSTM epilogue.
// W pre-permuted rows r' = 4*j + gate. Tile 64x16, grid (256,2), BK=128.
// Optional gpre (bf16 [128,4096] slice) added in epilogue.
// Lane split: gate0->dA(bf16), gate1->dB(bf16), gate2->cstate, gate3->dC(bf16) or dF(f32).
// =======================================================================
template<int TAG>
__global__ __launch_bounds__(256)
void gate_lstm(const bf16_t* __restrict__ A, int lda,
               const bf16_t* __restrict__ W, int ldw, int TT,
               const bf16_t* __restrict__ gpre,
               const float* __restrict__ cbias, float* __restrict__ cstate,
               bf16_t* __restrict__ dA, int ldA,
               bf16_t* __restrict__ dB, int ldB,
               bf16_t* __restrict__ dC, int ldC,
               float* __restrict__ dF)
{
    const int tid = threadIdx.x;
    const int w = tid >> 6, lane = tid & 63;
    const int llo = lane & 15, lhi = lane >> 4;
    const int nt = blockIdx.x;
    const int m0 = blockIdx.y * 64;
    const int n0 = nt * 16;

    __shared__ __align__(16) uint8_t smA[2][16384];
    __shared__ __align__(16) uint8_t smB[2][4096];

    f32x4 acc = {0.f, 0.f, 0.f, 0.f};
    uint4 ra[4], rb;

    auto load_tile = [&](int ti) {
        const int k0 = ti << 7;
        #pragma unroll
        for (int i = 0; i < 4; ++i) {
            const int q = tid + i * 256;
            const int row = q >> 4, c = q & 15;
            ra[i] = *(const uint4*)(A + (size_t)(m0 + row) * lda + k0 + c * 8);
        }
        {
            const int row = tid >> 4, c = tid & 15;
            rb = *(const uint4*)(W + (size_t)(n0 + row) * ldw + k0 + c * 8);
        }
    };
    auto write_tile = [&](int buf) {
        #pragma unroll
        for (int i = 0; i < 4; ++i) {
            const int q = tid + i * 256;
            const int row = q >> 4, c = q & 15;
            *(uint4*)(smA[buf] + row * 256 + ((c ^ (row & 7)) << 4)) = ra[i];
        }
        {
            const int row = tid >> 4, c = tid & 15;
            *(uint4*)(smB[buf] + row * 256 + ((c ^ (row & 7)) << 4)) = rb;
        }
    };
    auto compute = [&](int buf) {
        const int r7 = llo & 7;
        #pragma unroll
        for (int kk = 0; kk < 4; ++kk) {
            const int coff = ((kk * 4 + lhi) ^ r7) << 4;
            bf16x8 a  = *(const bf16x8*)(smA[buf] + (w * 16 + llo) * 256 + coff);
            bf16x8 bb = *(const bf16x8*)(smB[buf] + llo * 256 + coff);
            acc = __builtin_amdgcn_mfma_f32_16x16x32_bf16(a, bb, acc, 0, 0, 0);
        }
    };

    load_tile(0); write_tile(0);
    load_tile(1);
    __syncthreads();
    int cur = 0;
    for (int ti = 0; ti < TT; ++ti) {
        if (ti + 1 < TT) write_tile(cur ^ 1);
        if (ti + 2 < TT) load_tile(ti + 2);
        compute(cur);
        __syncthreads();
        cur ^= 1;
    }

    // ---- LSTM epilogue ----
    const int gate = llo & 3;
    const int jg   = nt * 4 + (llo >> 2);
    const float bsum = cbias[n0 + llo];
    const int base = lane & ~3;
    const int rowb = m0 + w * 16 + lhi * 4;
    float gadd[4] = {0.f, 0.f, 0.f, 0.f};
    if (gpre) {
        #pragma unroll
        for (int r = 0; r < 4; ++r)
            gadd[r] = (float)gpre[(size_t)(rowb + r) * G4 + n0 + llo];
    }
    #pragma unroll
    for (int r = 0; r < 4; ++r) {
        const float v  = acc[r] + bsum + gadd[r];
        const float gi = __shfl(v, base + 0);
        const float gf = __shfl(v, base + 1);
        const float gg = __shfl(v, base + 2);
        const float go = __shfl(v, base + 3);
        const int b = rowb + r;
        const float cold = cstate[b * CH + jg];
        const float si = 1.f / (1.f + expf(-gi));
        const float sf = 1.f / (1.f + expf(-gf));
        const float so = 1.f / (1.f + expf(-go));
        const float cn = sf * cold + si * tanhf(gg);
        const float hn = so * tanhf(cn);
        const bf16_t hb = (bf16_t)hn;
        if (gate == 0)      dA[(size_t)b * ldA + jg] = hb;
        else if (gate == 1) dB[(size_t)b * ldB + jg] = hb;
        else if (gate == 2) cstate[b * CH + jg] = cn;
        else {
            if (dC) dC[(size_t)b * ldC + jg] = hb;
            else    dF[b * CH + jg] = hn;
        }
    }
}

// ---------------- attention: hq + e + softmax + weighted sum ----------------
__global__ __launch_bounds__(256)
void attn_k(const float* __restrict__ p_att, const float* __restrict__ h_att_f,
            const bf16_t* __restrict__ h2att_wT, const float* __restrict__ h2att_b,
            const bf16_t* __restrict__ att_e, const float* __restrict__ alpha_w,
            const float* __restrict__ alpha_b, bf16_t* __restrict__ xl3_cur)
{
    __shared__ float sh[CH];
    __shared__ float shq[CAH];
    __shared__ float se[CNREG], salpha[CNREG];
    const int b = blockIdx.x, tid = threadIdx.x;

    for (int j = tid; j < CH; j += 256) sh[j] = h_att_f[b * CH + j];
    __syncthreads();

    // hq with 4-lane k-split (chain 256 instead of 1024)
    const int q4 = tid & 3, nn0 = tid >> 2;
    for (int n = nn0; n < CAH; n += 64) {
        const bf16_t* wrow = h2att_wT + (size_t)n * CH + q4 * 256;
        float s = 0.f;
        #pragma unroll 4
        for (int k = 0; k < 256; k += 8) {
            bf16x8 w8 = *(const bf16x8*)(wrow + k);
            #pragma unroll
            for (int j = 0; j < 8; ++j) s = fmaf((float)w8[j], sh[q4 * 256 + k + j], s);
        }
        s += __shfl_xor(s, 1);
        s += __shfl_xor(s, 2);
        if (q4 == 0) shq[n] = s + h2att_b[n];
    }
    __syncthreads();

    const int wave = tid >> 6, lane = tid & 63;
    for (int n = wave; n < CNREG; n += 4) {
        const float* pr = p_att + ((size_t)b * CNREG + n) * CAH;
        float s = 0.f;
        #pragma unroll
        for (int q = 0; q < CAH / 64; ++q) {
            const int d = lane + q * 64;
            s += alpha_w[d] * tanhf(pr[d] + shq[d]);
        }
        for (int off = 32; off; off >>= 1) s += __shfl_down(s, off);
        if (lane == 0) se[n] = s + alpha_b[0];
    }
    __syncthreads();

    float mx = -1e30f;
    for (int n = 0; n < CNREG; ++n) mx = fmaxf(mx, se[n]);
    float sum = 0.f;
    for (int n = 0; n < CNREG; ++n) sum += expf(se[n] - mx);
    if (tid < CNREG) salpha[tid] = expf(se[tid] - mx) / sum;
    __syncthreads();

    // PV: coalesced bf16x4 loads, 4 cols per thread
    const int d0 = tid * 4;
    float a0 = 0.f, a1 = 0.f, a2 = 0.f, a3 = 0.f;
    const bf16_t* ae = att_e + (size_t)b * CNREG * CFE + d0;
    #pragma unroll 4
    for (int n = 0; n < CNREG; ++n) {
        bf16x4 v = *(const bf16x4*)(ae + (size_t)n * CFE);
        const float al = salpha[n];
        a0 = fmaf(al, (float)v[0], a0);
        a1 = fmaf(al, (float)v[1], a1);
        a2 = fmaf(al, (float)v[2], a2);
        a3 = fmaf(al, (float)v[3], a3);
    }
    bf16x4 o = { (bf16_t)a0, (bf16_t)a1, (bf16_t)a2, (bf16_t)a3 };
    *(bf16x4*)(xl3_cur + (size_t)b * XL3 + d0) = o;
}

// ---------------- prep kernels ----------------
__global__ void convert_pad(const float* __restrict__ src, bf16_t* __restrict__ dst,
                            int C, int Cp)
{
    const int r = blockIdx.y;
    const int c = blockIdx.x * 256 + threadIdx.x;
    if (c >= Cp) return;
    dst[(size_t)r * Cp + c] = (c < C) ? (bf16_t)src[(size_t)r * C + c] : (bf16_t)0.f;
}

// gate-interleave row perm + column-block copy: dst[r'][dcol0+c] = src[rs][scol0+c]
__global__ void convert_perm(const float* __restrict__ src, int srcld, int scol0,
                             int valid, bf16_t* __restrict__ dst, int dstld, int dcol0,
                             int ncols)
{
    const int rp = blockIdx.y;
    const int c = blockIdx.x * 256 + threadIdx.x;
    if (c >= ncols) return;
    const int rs = (rp & 3) * 1024 + (rp >> 2);
    const float v = (c < valid) ? src[(size_t)rs * srcld + scol0 + c] : 0.f;
    dst[(size_t)rp * dstld + dcol0 + c] = (bf16_t)v;
}

__global__ void bias_perm(const float* __restrict__ bih, const float* __restrict__ bhh,
                          float* __restrict__ dst)
{
    const int rp = blockIdx.x * 256 + threadIdx.x;
    if (rp >= G4) return;
    const int rs = (rp & 3) * 1024 + (rp >> 2);
    dst[rp] = bih[rs] + bhh[rs];
}

__global__ __launch_bounds__(256)
void transpose_convert(const float* __restrict__ src, bf16_t* __restrict__ dst,
                       int K, int N)
{
    __shared__ float tile[32][33];
    const int n0 = blockIdx.x * 32, k0 = blockIdx.y * 32;
    const int tx = threadIdx.x & 31, ty = threadIdx.x >> 5;
    #pragma unroll
    for (int i = 0; i < 4; ++i) {
        const int k = k0 + ty + i * 8, n = n0 + tx;
        tile[ty + i * 8][tx] = (k < K && n < N) ? src[(size_t)k * N + n] : 0.f;
    }
    __syncthreads();
    #pragma unroll
    for (int i = 0; i < 4; ++i) {
        const int n = n0 + ty + i * 8, k = k0 + tx;
        if (n < N && k < K) dst[(size_t)n * K + k] = (bf16_t)tile[tx][ty + i * 8];
    }
}

// emb -> xw_all[:, 1024:2048] (relu, pad)
__global__ void emb_all(const float* __restrict__ emb_w,
                        const int* __restrict__ captions, bf16_t* __restrict__ xw_all)
{
    const int r = blockIdx.y;                       // t*128 + b
    const int j = blockIdx.x * 256 + threadIdx.x;   // 0..1023
    const int t = r >> 7, b = r & 127;
    const int tok = captions[b * CT + t];
    const float v = (j < CWE) ? fmaxf(emb_w[(size_t)tok * CWE + j], 0.f) : 0.f;
    xw_all[(size_t)r * 2048 + 1024 + j] = (bf16_t)v;
}

// replicate fc_e 16x -> xw_all[:, 0:1024]
__global__ void fc_rep(const bf16_t* __restrict__ fc_e, bf16_t* __restrict__ xw_all)
{
    const int r = blockIdx.y;
    const int j = blockIdx.x * 256 + threadIdx.x;
    if (j >= 1024) return;
    xw_all[(size_t)r * 2048 + j] = fc_e[(size_t)(r & 127) * 1024 + j];
}

// ---- in-place log-softmax over each of 2048 rows of out ----
__global__ __launch_bounds__(256)
void logsoftmax_inplace(float* __restrict__ out)
{
    __shared__ float red[4];
    const int r = blockIdx.x, tid = threadIdx.x;
    float* row = out + (size_t)r * CV;
    constexpr int NI = 47;

    float v[NI];
    float mx = -1e30f;
    #pragma unroll
    for (int i = 0; i < NI; ++i) {
        const int j = tid + i * 256;
        v[i] = (j < CV) ? row[j] : -1e30f;
        mx = fmaxf(mx, v[i]);
    }
    for (int off = 32; off; off >>= 1) mx = fmaxf(mx, __shfl_down(mx, off));
    if ((tid & 63) == 0) red[tid >> 6] = mx;
    __syncthreads();
    mx = fmaxf(fmaxf(red[0], red[1]), fmaxf(red[2], red[3]));
    __syncthreads();

    float sum = 0.f;
    #pragma unroll
    for (int i = 0; i < NI; ++i)
        if (tid + i * 256 < CV) sum += expf(v[i] - mx);
    for (int off = 32; off; off >>= 1) sum += __shfl_down(sum, off);
    if ((tid & 63) == 0) red[tid >> 6] = sum;
    __syncthreads();
    sum = red[0] + red[1] + red[2] + red[3];
    const float lse = mx + logf(sum);

    #pragma unroll
    for (int i = 0; i < NI; ++i) {
        const int j = tid + i * 256;
        if (j < CV) row[j] = v[i] - lse;
    }
}

// ---------------- launch ----------------
extern "C" void kernel_launch(void* const* d_in, const int* in_sizes, int n_in,
                              void* d_out, int out_size, void* d_ws, size_t ws_size,
                              hipStream_t stream)
{
    const float* fc_feats  = (const float*)d_in[0];
    const float* att_feats = (const float*)d_in[1];
    const int*   captions  = (const int*)  d_in[2];
    const float* emb_w     = (const float*)d_in[3];
    const float* fc_w      = (const float*)d_in[4];
    const float* fc_b      = (const float*)d_in[5];
    const float* atte_w    = (const float*)d_in[6];
    const float* atte_b    = (const float*)d_in[7];
    const float* ctx_w     = (const float*)d_in[8];
    const float* ctx_b     = (const float*)d_in[9];
    const float* attl_wih  = (const float*)d_in[10];
    const float* attl_whh  = (const float*)d_in[11];
    const float* attl_bih  = (const float*)d_in[12];
    const float* attl_bhh  = (const float*)d_in[13];
    const float* h2att_w   = (const float*)d_in[14];
    const float* h2att_b   = (const float*)d_in[15];
    const float* alpha_w   = (const float*)d_in[16];
    const float* alpha_b   = (const float*)d_in[17];
    const float* langl_wih = (const float*)d_in[18];
    const float* langl_whh = (const float*)d_in[19];
    const float* langl_bih = (const float*)d_in[20];
    const float* langl_bhh = (const float*)d_in[21];
    const float* cls_w     = (const float*)d_in[22];
    const float* cls_b     = (const float*)d_in[23];

    float* out = (float*)d_out;

    // ---- workspace layout ----
    char* p = (char*)d_ws;
    auto alloc_bf = [&](size_t e) { bf16_t* q = (bf16_t*)p; p += e * 2; return q; };
    auto alloc_f  = [&](size_t e) { float*  q = (float*) p; p += e * 4; return q; };

    bf16_t* Wcat_att    = alloc_bf((size_t)G4 * XH);      // [4096][2048] perm rows
    bf16_t* Wcat_lang   = alloc_bf((size_t)G4 * XL3);     // [4096][3072] perm rows
    bf16_t* Win_att     = alloc_bf((size_t)G4 * 2048);    // [4096][2048] perm: [fc | emb]
    bf16_t* fc_wT_b     = alloc_bf((size_t)CFE * CFEAT);
    bf16_t* atte_wT_b   = alloc_bf((size_t)CFE * CFEAT);
    bf16_t* ctx_wT_b    = alloc_bf((size_t)CAH * CFE);
    bf16_t* h2att_wT_b  = alloc_bf((size_t)CAH * CH);
    bf16_t* cls_wT_b    = alloc_bf((size_t)CVP * CH);
    bf16_t* fc_feats_b  = alloc_bf((size_t)CB * CFEAT);
    bf16_t* att_feats_b = alloc_bf((size_t)CB * CNREG * CFEAT);  // Gpre aliases this
    bf16_t* att_e_b     = alloc_bf((size_t)CB * CNREG * CFE);
    bf16_t* xw_all      = alloc_bf((size_t)(CT - 1) * CB * 2048);
    bf16_t* fc_e_b      = alloc_bf((size_t)CB * CFE);
    bf16_t* xh0         = alloc_bf((size_t)CB * XH);
    bf16_t* xh1         = alloc_bf((size_t)CB * XH);
    bf16_t* xl3a        = alloc_bf((size_t)CB * XL3);
    bf16_t* xl3b        = alloc_bf((size_t)CB * XL3);
    bf16_t* h_all       = alloc_bf((size_t)CB * (CT - 1) * CH);
    float*  p_att       = alloc_f ((size_t)CB * CNREG * CAH);
    float*  h_att_f     = alloc_f ((size_t)CB * CH);
    float*  cbias_att   = alloc_f (G4);
    float*  cbias_lang  = alloc_f (G4);
    float*  c_att       = alloc_f ((size_t)CB * CH);
    float*  c_lang      = alloc_f ((size_t)CB * CH);

    bf16_t* Gpre = att_feats_b;   // alias: att_feats_b dead after att_e GEMM (16MB <= 18MB)

    // ---- zero state ----
    hipMemsetAsync(xh0,    0, (size_t)CB * XH * 2, stream);
    hipMemsetAsync(xh1,    0, (size_t)CB * XH * 2, stream);
    hipMemsetAsync(xl3a,   0, (size_t)CB * XL3 * 2, stream);
    hipMemsetAsync(xl3b,   0, (size_t)CB * XL3 * 2, stream);
    hipMemsetAsync(c_att,  0, (size_t)CB * CH * 4, stream);
    hipMemsetAsync(c_lang, 0, (size_t)CB * CH * 4, stream);
    hipMemsetAsync(cls_wT_b + (size_t)CV * CH, 0, (size_t)(CVP - CV) * CH * 2, stream);

    const dim3 blk(256);
    auto mk = [](const bf16_t* A, int lda, const bf16_t* W, int ldw, int kt) {
        return Seg{A, W, lda, ldw, kt};
    };

    // ---- one-time weight prep ----
    // Wcat_att = [attl_wih[:,0:1024] | attl_whh], perm rows
    convert_perm<<<dim3(4, G4), blk, 0, stream>>>(attl_wih, 3048, 0, 1024, Wcat_att, XH, 0, 1024);
    convert_perm<<<dim3(4, G4), blk, 0, stream>>>(attl_whh, 1024, 0, 1024, Wcat_att, XH, 1024, 1024);
    // Win_att = [attl_wih[:,1024:2048] | attl_wih[:,2048:3048]+pad], perm rows
    convert_perm<<<dim3(4, G4), blk, 0, stream>>>(attl_wih, 3048, 1024, 1024, Win_att, 2048, 0, 1024);
    convert_perm<<<dim3(4, G4), blk, 0, stream>>>(attl_wih, 3048, 2048, 1000, Win_att, 2048, 1024, 1024);
    // Wcat_lang = [langl_wih | langl_whh], perm rows
    convert_perm<<<dim3(8, G4), blk, 0, stream>>>(langl_wih, 2048, 0, 2048, Wcat_lang, XL3, 0, 2048);
    convert_perm<<<dim3(4, G4), blk, 0, stream>>>(langl_whh, 1024, 0, 1024, Wcat_lang, XL3, 2048, 1024);
    bias_perm<<<16, blk, 0, stream>>>(attl_bih, attl_bhh, cbias_att);
    bias_perm<<<16, blk, 0, stream>>>(langl_bih, langl_bhh, cbias_lang);
    convert_pad<<<dim3(8, CB), blk, 0, stream>>>(fc_feats, fc_feats_b, CFEAT, CFEAT);
    convert_pad<<<dim3(8, CB * CNREG), blk, 0, stream>>>(att_feats, att_feats_b, CFEAT, CFEAT);
    transpose_convert<<<dim3(CFE/32, CFEAT/32), blk, 0, stream>>>(fc_w,    fc_wT_b,    CFEAT, CFE);
    transpose_convert<<<dim3(CFE/32, CFEAT/32), blk, 0, stream>>>(atte_w,  atte_wT_b,  CFEAT, CFE);
    transpose_convert<<<dim3(CAH/32, CFE/32),   blk, 0, stream>>>(ctx_w,   ctx_wT_b,   CFE,   CAH);
    transpose_convert<<<dim3(CAH/32, CH/32),    blk, 0, stream>>>(h2att_w, h2att_wT_b, CH,    CAH);
    transpose_convert<<<dim3(CDIV(CV,32), CH/32), blk, 0, stream>>>(cls_w, cls_wT_b,   CH,    CV);
    emb_all<<<dim3(4, (CT - 1) * CB), blk, 0, stream>>>(emb_w, captions, xw_all);

    // ---- preamble GEMMs ----
    // fc_e = relu(fc_feats @ fc_w + b)  [128,1024] bf16
    pre_gemm<true,true><<<16, blk, 0, stream>>>(
        mk(fc_feats_b, CFEAT, fc_wT_b, CFEAT, 32), 1, fc_b, fc_e_b, CFE);
    // att_e = relu(att_feats @ atte_w + b)  [4608,1024] bf16  (last use of att_feats_b)
    pre_gemm<true,true><<<576, blk, 0, stream>>>(
        mk(att_feats_b, CFEAT, atte_wT_b, CFEAT, 32), 36, atte_b, att_e_b, CFE);
    // p_att = att_e @ ctx_w + b  [4608,512] fp32
    pre_gemm<false,false><<<288, blk, 0, stream>>>(
        mk(att_e_b, CFE, ctx_wT_b, CFE, 16), 36, ctx_b, p_att, CAH);
    // xw_all[:,0:1024] = fc_e (replicated 16x)
    fc_rep<<<dim3(4, (CT - 1) * CB), blk, 0, stream>>>(fc_e_b, xw_all);
    // Gpre = xw_all @ Win_att^T  [2048,4096] bf16  (overwrites att_feats_b)
    pre_gemm<false,true><<<1024, blk, 0, stream>>>(
        mk(xw_all, 2048, Win_att, 2048, 32), 16, nullptr, Gpre, G4);

    // ---- recurrence: 3 launches per step (ping-pong buffers) ----
    for (int t = 0; t < CT - 1; ++t) {
        bf16_t* xh_cur  = (t & 1) ? xh1 : xh0;
        bf16_t* xh_nxt  = (t & 1) ? xh0 : xh1;
        bf16_t* xl_cur  = (t & 1) ? xl3b : xl3a;
        bf16_t* xl_nxt  = (t & 1) ? xl3a : xl3b;

        // att-LSTM: A = xh_cur [h_lang|h_att], K=2048 (16 tiles) + Gpre[t]
        gate_lstm<0><<<dim3(256, 2), blk, 0, stream>>>(
            xh_cur, XH, Wcat_att, XH, 16,
            Gpre + (size_t)t * CB * G4,
            cbias_att, c_att,
            xh_nxt + 1024, XH,        // h_att for next step's att gates
            xl_cur + 1024, XL3,       // h_att for this step's lang gates
            nullptr, 0,
            h_att_f);                 // fp32 h_att for attention

        attn_k<<<CB, blk, 0, stream>>>(
            p_att, h_att_f, h2att_wT_b, h2att_b, att_e_b, alpha_w, alpha_b, xl_cur);

        // lang-LSTM: A = xl_cur [att_res|h_att|h_lang_prev], K=3072 (24 tiles)
        gate_lstm<1><<<dim3(256, 2), blk, 0, stream>>>(
            xl_cur, XL3, Wcat_lang, XL3, 24,
            nullptr,
            cbias_lang, c_lang,
            xh_nxt, XH,                       // h_lang for next att gates
            xl_nxt + 2048, XL3,               // h_lang_prev for next lang gates
            h_all + (size_t)t * CH, 16384,    // h_all[b][t][:]
            nullptr);
    }

    // ---- deferred classifier + log-softmax ----
    cls_gemm<<<1504, blk, 0, stream>>>(h_all, cls_wT_b, cls_b, out);
    logsoftmax_inplace<<<2048, blk, 0, stream>>>(out);
}